// Round 9
// baseline (157.439 us; speedup 1.0000x reference)
//
#include <hip/hip_runtime.h>

// FactorizedSpectralConv2d: B=16, CIN=COUT=64, H=W=128, MH=MW=32, super_res=1
// kAB (W-rDFT GEMM fused with folded H-DFT) -> kC (channel mix, float4 loads)
// -> kD (inv H-DFT, folded, sums YF0+YF1) -> kE (inv W-rDFT + bias, GEMM).
// ws layout (64 MiB): XF[48,64) ; YF0[0,16) ; YF1[16,32) ; Z[32,64) (XF dead)

__device__ __forceinline__ void build_tab(float* tabs) {
    int t = threadIdx.x;
    if (t < 128) {
        float ang = (float)t * 0.049087385212340517f;  // 2*pi/128
        float s, c;
        sincosf(ang, &s, &c);
        tabs[t] = c;        // cos at [0..127]
        tabs[129 + t] = s;  // sin at [129..256]
    }
}

// ---- kAB: fused W-rDFT (per (b,ci) image) + folded H-DFT ------------------
// Phase 1 (kA): A[h][q=2kx+p] = rDFT_W(x)[kx] via LDS GEMM, acc in regs.
// Fold: thread holds (h, h+64) pairs -> write Af planes directly to LDS:
//   p0=A[2m]+A[2m+64], p1=A[2m]-A[2m+64], p2=A[2m+1]+A[2m+65], p3=A[2m+1]-A[2m+65]
// Phase 2 (kB): XF rows k & 64-k from shared chains P1..P4; row 32 epilogue.
__global__ __launch_bounds__(256) void kAB(const float* __restrict__ x,
                                           float* __restrict__ XF) {
    __shared__ float tabs[258];
    __shared__ __align__(16) float smem[8256];  // Twid[0,4096) | xeo[4096,8256); later Af[0,8192)
    build_tab(tabs);
    __syncthreads();
    int t = threadIdx.x;
    size_t bc = blockIdx.x;  // b*64+ci, 1024 blocks
    float* Twid = smem;
    float* xeo  = smem + 4096;
    #pragma unroll
    for (int i = 0; i < 16; ++i) {
        int e = t + i * 256;
        int w = e >> 6, q = e & 63, kx = q >> 1;
        int idx = (w * kx) & 127;
        Twid[e] = (q & 1) ? -tabs[129 + idx] : tabs[idx];
    }
    const float* xb = x + bc * 16384;
    int th = t & 15;
    int tq = t >> 4;
    int q0 = tq * 4;
    int wl4 = (t & 3) * 4;
    int hb  = t >> 2;
    auto stage = [&](int ph) {
        #pragma unroll
        for (int it = 0; it < 2; ++it) {
            int h = it * 64 + hb;
            float4 lo = *(const float4*)(xb + h * 128 + ph * 16 + wl4);
            float4 hi = *(const float4*)(xb + h * 128 + ph * 16 + wl4 + 64);
            *(float2*)(&xeo[(wl4 + 0) * 260 + 2 * h]) = make_float2(lo.x + hi.x, lo.x - hi.x);
            *(float2*)(&xeo[(wl4 + 1) * 260 + 2 * h]) = make_float2(lo.y + hi.y, lo.y - hi.y);
            *(float2*)(&xeo[(wl4 + 2) * 260 + 2 * h]) = make_float2(lo.z + hi.z, lo.z - hi.z);
            *(float2*)(&xeo[(wl4 + 3) * 260 + 2 * h]) = make_float2(lo.w + hi.w, lo.w - hi.w);
        }
    };
    stage(0);
    float4 acc8[8];
    #pragma unroll
    for (int j = 0; j < 8; ++j) acc8[j] = make_float4(0.f, 0.f, 0.f, 0.f);
    for (int ph = 0; ph < 4; ++ph) {
        __syncthreads();
        #pragma unroll 4
        for (int wl = 0; wl < 16; ++wl) {
            int w = ph * 16 + wl;
            float4 tw = *(const float4*)(&Twid[w * 64 + q0]);
            const float* xr = &xeo[wl * 260 + 4 * th];
            #pragma unroll
            for (int i = 0; i < 4; ++i) {
                float4 d = *(const float4*)(xr + 64 * i);
                acc8[2*i].x   = fmaf(d.x, tw.x, acc8[2*i].x);
                acc8[2*i].y   = fmaf(d.x, tw.y, acc8[2*i].y);
                acc8[2*i].z   = fmaf(d.y, tw.z, acc8[2*i].z);
                acc8[2*i].w   = fmaf(d.y, tw.w, acc8[2*i].w);
                acc8[2*i+1].x = fmaf(d.z, tw.x, acc8[2*i+1].x);
                acc8[2*i+1].y = fmaf(d.z, tw.y, acc8[2*i+1].y);
                acc8[2*i+1].z = fmaf(d.w, tw.z, acc8[2*i+1].z);
                acc8[2*i+1].w = fmaf(d.w, tw.w, acc8[2*i+1].w);
            }
        }
        __syncthreads();
        if (ph < 3) stage(ph + 1);
    }
    // In-register fold -> Af planes in LDS (overlays Twid/xeo; all reads done).
    // h = 32i + 2th + r = acc8[2i+r]; pair (h, h+64) = (acc8[2i+r], acc8[2i+4+r]).
    float* Af = smem;
    #pragma unroll
    for (int i = 0; i < 2; ++i) {
        int m = 16 * i + th;  // h = 2m (r=0), 2m+1 (r=1)
        float4 a = acc8[2*i],     b = acc8[2*i + 4];
        float4 c = acc8[2*i + 1], d = acc8[2*i + 5];
        *(float4*)(&Af[       m*64 + q0]) = make_float4(a.x+b.x, a.y+b.y, a.z+b.z, a.w+b.w);
        *(float4*)(&Af[2048 + m*64 + q0]) = make_float4(a.x-b.x, a.y-b.y, a.z-b.z, a.w-b.w);
        *(float4*)(&Af[4096 + m*64 + q0]) = make_float4(c.x+d.x, c.y+d.y, c.z+d.z, c.w+d.w);
        *(float4*)(&Af[6144 + m*64 + q0]) = make_float4(c.x-d.x, c.y-d.y, c.z-d.z, c.w-d.w);
    }
    __syncthreads();
    // ---- kB compute part ----
    {
        int k = t & 31, kxg = t >> 5;
        int kx0 = kxg * 4;
        int sig = k & 1;
        const float* pe = Af + sig * 2048;
        const float* po = Af + 4096 + sig * 2048;
        float4 P1 = {0,0,0,0}, P2 = {0,0,0,0}, P3 = {0,0,0,0}, P4 = {0,0,0,0};
        int idx_e = 0;
        for (int m = 0; m < 32; ++m) {
            float ce = tabs[idx_e], se = tabs[129 + idx_e];
            int idx_o = (idx_e + k) & 127;
            float co_ = tabs[idx_o], so_ = tabs[129 + idx_o];
            idx_e = (idx_e + 2 * k) & 127;
            float4 ae01 = *(const float4*)(pe + m * 64 + 2 * kx0);
            float4 ae23 = *(const float4*)(pe + m * 64 + 2 * kx0 + 4);
            float4 ao01 = *(const float4*)(po + m * 64 + 2 * kx0);
            float4 ao23 = *(const float4*)(po + m * 64 + 2 * kx0 + 4);
            P1.x = fmaf(ae01.x, ce, P1.x); P1.x = fmaf(ao01.x, co_, P1.x);
            P2.x = fmaf(ae01.y, se, P2.x); P2.x = fmaf(ao01.y, so_, P2.x);
            P3.x = fmaf(ae01.y, ce, P3.x); P3.x = fmaf(ao01.y, co_, P3.x);
            P4.x = fmaf(ae01.x, se, P4.x); P4.x = fmaf(ao01.x, so_, P4.x);
            P1.y = fmaf(ae01.z, ce, P1.y); P1.y = fmaf(ao01.z, co_, P1.y);
            P2.y = fmaf(ae01.w, se, P2.y); P2.y = fmaf(ao01.w, so_, P2.y);
            P3.y = fmaf(ae01.w, ce, P3.y); P3.y = fmaf(ao01.w, co_, P3.y);
            P4.y = fmaf(ae01.z, se, P4.y); P4.y = fmaf(ao01.z, so_, P4.y);
            P1.z = fmaf(ae23.x, ce, P1.z); P1.z = fmaf(ao23.x, co_, P1.z);
            P2.z = fmaf(ae23.y, se, P2.z); P2.z = fmaf(ao23.y, so_, P2.z);
            P3.z = fmaf(ae23.y, ce, P3.z); P3.z = fmaf(ao23.y, co_, P3.z);
            P4.z = fmaf(ae23.x, se, P4.z); P4.z = fmaf(ao23.x, so_, P4.z);
            P1.w = fmaf(ae23.z, ce, P1.w); P1.w = fmaf(ao23.z, co_, P1.w);
            P2.w = fmaf(ae23.w, se, P2.w); P2.w = fmaf(ao23.w, so_, P2.w);
            P3.w = fmaf(ae23.w, ce, P3.w); P3.w = fmaf(ao23.w, co_, P3.w);
            P4.w = fmaf(ae23.z, se, P4.w); P4.w = fmaf(ao23.z, so_, P4.w);
        }
        float* xfb = XF + bc * 4096;
        *(float4*)(xfb + (k * 32 + kx0) * 2) =
            make_float4(P1.x + P2.x, P3.x - P4.x, P1.y + P2.y, P3.y - P4.y);
        *(float4*)(xfb + (k * 32 + kx0) * 2 + 4) =
            make_float4(P1.z + P2.z, P3.z - P4.z, P1.w + P2.w, P3.w - P4.w);
        if (k) {
            *(float4*)(xfb + ((64 - k) * 32 + kx0) * 2) =
                make_float4(P1.x - P2.x, P3.x + P4.x, P1.y - P2.y, P3.y + P4.y);
            *(float4*)(xfb + ((64 - k) * 32 + kx0) * 2 + 4) =
                make_float4(P1.z - P2.z, P3.z + P4.z, P1.w - P2.w, P3.w + P4.w);
        }
        if (t < 32) {
            int kx = t;
            float re = 0.f, im = 0.f;
            #pragma unroll 8
            for (int m = 0; m < 32; ++m) {
                float2 aep = *(const float2*)(&Af[       m * 64 + 2 * kx]);
                float2 aop = *(const float2*)(&Af[4096 + m * 64 + 2 * kx]);
                float sg = (m & 1) ? -1.f : 1.f;
                re = fmaf(sg, aep.x - aop.y, re);
                im = fmaf(sg, aep.y + aop.x, im);
            }
            xfb[(32 * 32 + kx) * 2]     = re;
            xfb[(32 * 32 + kx) * 2 + 1] = im;
        }
    }
}

// ---- kC: channel mix, ci-split (2 partials) + float4 prefetch. ------------
__global__ __launch_bounds__(256) void kC(const float* __restrict__ XF,
                                          const float* __restrict__ Wgt,
                                          float* __restrict__ YF0,
                                          float* __restrict__ YF1) {
    __shared__ float2 Xs[2048];  // [ci_l][b][mx], 16 KB
    __shared__ float2 Ws[2048];  // [ci_l][co_l][mx], 16 KB
    int t = threadIdx.x;
    int bid = blockIdx.x;
    int cih = bid & 1;
    int mxh = (bid >> 1) & 1;
    int cot = (bid >> 2) & 3;
    int my  = (bid >> 4) & 31;
    int c   = bid >> 9;
    int co0 = cot * 16;
    int slotbase = (c * 32 + my) * 32 + mxh * 16;
    int mx = t & 15;
    int b  = t >> 4;
    float2 acc[16];
    #pragma unroll
    for (int i = 0; i < 16; ++i) acc[i] = make_float2(0.f, 0.f);
    const size_t wre_base = (size_t)c * 4096 * 1024 + (size_t)my * 32 + mxh * 16;
    const size_t wim_base = wre_base + (size_t)2 * 4096 * 1024;
    float4 rx4[4], rwre[2], rwim[2];
    auto loadc = [&](int cc) {
        #pragma unroll
        for (int s = 0; s < 4; ++s) {
            int e4 = t + s * 256;  // 0..1023: [eci 8][eb 16][emx2 8]
            int emx2 = e4 & 7, eb = (e4 >> 3) & 15, eci = e4 >> 7;
            int ci = cih * 32 + cc * 8 + eci;
            rx4[s] = *(const float4*)(XF + ((size_t)(eb * 64 + ci) * 2048 + slotbase + emx2 * 2) * 2);
        }
        #pragma unroll
        for (int s = 0; s < 2; ++s) {
            int e2 = t + s * 256;  // 0..511: [eci 8][eco 16][emxg 4]
            int emxg = e2 & 3, eco = (e2 >> 2) & 15, eci = e2 >> 6;
            int ci = cih * 32 + cc * 8 + eci;
            size_t g = (size_t)ci * 64 + co0 + eco;
            rwre[s] = *(const float4*)(Wgt + wre_base + g * 1024 + emxg * 4);
            rwim[s] = *(const float4*)(Wgt + wim_base + g * 1024 + emxg * 4);
        }
    };
    loadc(0);
    for (int cc = 0; cc < 4; ++cc) {
        #pragma unroll
        for (int s = 0; s < 4; ++s) {
            int e4 = t + s * 256;
            int emx2 = e4 & 7, eb = (e4 >> 3) & 15, eci = e4 >> 7;
            *(float4*)(&Xs[(eci * 16 + eb) * 16 + emx2 * 2]) = rx4[s];
        }
        #pragma unroll
        for (int s = 0; s < 2; ++s) {
            int e2 = t + s * 256;
            int emxg = e2 & 3, eco = (e2 >> 2) & 15, eci = e2 >> 6;
            float2* wp = &Ws[(eci * 16 + eco) * 16 + emxg * 4];
            *(float4*)(wp)     = make_float4(rwre[s].x, rwim[s].x, rwre[s].y, rwim[s].y);
            *(float4*)(wp + 2) = make_float4(rwre[s].z, rwim[s].z, rwre[s].w, rwim[s].w);
        }
        __syncthreads();
        if (cc < 3) loadc(cc + 1);
        #pragma unroll
        for (int ci_l = 0; ci_l < 8; ++ci_l) {
            float2 xv = Xs[(ci_l * 16 + b) * 16 + mx];
            #pragma unroll
            for (int co_l = 0; co_l < 16; ++co_l) {
                float2 w = Ws[(ci_l * 16 + co_l) * 16 + mx];
                acc[co_l].x = fmaf(xv.x, w.x, acc[co_l].x);
                acc[co_l].x = fmaf(-xv.y, w.y, acc[co_l].x);
                acc[co_l].y = fmaf(xv.x, w.y, acc[co_l].y);
                acc[co_l].y = fmaf(xv.y, w.x, acc[co_l].y);
            }
        }
        __syncthreads();
    }
    float* YF = cih ? YF1 : YF0;
    #pragma unroll
    for (int co_l = 0; co_l < 16; ++co_l) {
        *(float2*)(YF + ((size_t)(b * 64 + co0 + co_l) * 2048 + slotbase + mx) * 2) = acc[co_l];
    }
}

// ---- kD (folded): Z[h][kx] = Σ_{k=0..32} C_k(h)·Q[k] + i·S_k(h)·R[k] ------
__global__ __launch_bounds__(256) void kD(const float* __restrict__ YF0,
                                          const float* __restrict__ YF1,
                                          float* __restrict__ Z) {
    __shared__ float tabs[258];
    __shared__ __align__(16) float Qs[33 * 64];
    __shared__ __align__(16) float Rs[33 * 64];
    build_tab(tabs);
    int t = threadIdx.x;
    size_t bo = blockIdx.x;
    const float* y0 = YF0 + bo * 4096;
    const float* y1 = YF1 + bo * 4096;
    for (int u = t; u < 528; u += 256) {
        int k = u >> 4, kxf = (u & 15) * 4;
        float4 a0 = *(const float4*)(y0 + k * 64 + kxf);
        float4 a1 = *(const float4*)(y1 + k * 64 + kxf);
        float4 a = make_float4(a0.x+a1.x, a0.y+a1.y, a0.z+a1.z, a0.w+a1.w);
        float4 Q, R;
        if (k == 0) { Q = a; R = make_float4(0.f, 0.f, 0.f, 0.f); }
        else if (k == 32) { Q = a; R = make_float4(-a.x, -a.y, -a.z, -a.w); }
        else {
            float4 b0 = *(const float4*)(y0 + (64 - k) * 64 + kxf);
            float4 b1 = *(const float4*)(y1 + (64 - k) * 64 + kxf);
            float4 bb = make_float4(b0.x+b1.x, b0.y+b1.y, b0.z+b1.z, b0.w+b1.w);
            Q = make_float4(a.x+bb.x, a.y+bb.y, a.z+bb.z, a.w+bb.w);
            R = make_float4(a.x-bb.x, a.y-bb.y, a.z-bb.z, a.w-bb.w);
        }
        *(float4*)(&Qs[k * 64 + kxf]) = Q;
        *(float4*)(&Rs[k * 64 + kxf]) = R;
    }
    __syncthreads();
    int hh = t >> 2;
    int kx0 = (t & 3) * 8;
    float4 Ee0 = {0,0,0,0}, Ee1 = {0,0,0,0}, Ee2 = {0,0,0,0}, Ee3 = {0,0,0,0};
    float4 Eo0 = {0,0,0,0}, Eo1 = {0,0,0,0}, Eo2 = {0,0,0,0}, Eo3 = {0,0,0,0};
    int idx = 0;
#define KD_BODY(E0, E1, E2, E3, kk)                                          \
    {                                                                        \
        float c = tabs[idx], s = tabs[129 + idx];                            \
        const float4* Qp = (const float4*)(&Qs[(kk) * 64 + kx0 * 2]);        \
        const float4* Rp = (const float4*)(&Rs[(kk) * 64 + kx0 * 2]);        \
        float4 Qv, Rv;                                                       \
        Qv = Qp[0]; Rv = Rp[0];                                              \
        E0.x = fmaf(c, Qv.x, E0.x); E0.x = fmaf(-s, Rv.y, E0.x);             \
        E0.y = fmaf(c, Qv.y, E0.y); E0.y = fmaf(s, Rv.x, E0.y);              \
        E0.z = fmaf(c, Qv.z, E0.z); E0.z = fmaf(-s, Rv.w, E0.z);             \
        E0.w = fmaf(c, Qv.w, E0.w); E0.w = fmaf(s, Rv.z, E0.w);              \
        Qv = Qp[1]; Rv = Rp[1];                                              \
        E1.x = fmaf(c, Qv.x, E1.x); E1.x = fmaf(-s, Rv.y, E1.x);             \
        E1.y = fmaf(c, Qv.y, E1.y); E1.y = fmaf(s, Rv.x, E1.y);              \
        E1.z = fmaf(c, Qv.z, E1.z); E1.z = fmaf(-s, Rv.w, E1.z);             \
        E1.w = fmaf(c, Qv.w, E1.w); E1.w = fmaf(s, Rv.z, E1.w);              \
        Qv = Qp[2]; Rv = Rp[2];                                              \
        E2.x = fmaf(c, Qv.x, E2.x); E2.x = fmaf(-s, Rv.y, E2.x);             \
        E2.y = fmaf(c, Qv.y, E2.y); E2.y = fmaf(s, Rv.x, E2.y);              \
        E2.z = fmaf(c, Qv.z, E2.z); E2.z = fmaf(-s, Rv.w, E2.z);             \
        E2.w = fmaf(c, Qv.w, E2.w); E2.w = fmaf(s, Rv.z, E2.w);              \
        Qv = Qp[3]; Rv = Rp[3];                                              \
        E3.x = fmaf(c, Qv.x, E3.x); E3.x = fmaf(-s, Rv.y, E3.x);             \
        E3.y = fmaf(c, Qv.y, E3.y); E3.y = fmaf(s, Rv.x, E3.y);              \
        E3.z = fmaf(c, Qv.z, E3.z); E3.z = fmaf(-s, Rv.w, E3.z);             \
        E3.w = fmaf(c, Qv.w, E3.w); E3.w = fmaf(s, Rv.z, E3.w);              \
        idx = (idx + hh) & 127;                                              \
    }
    for (int u = 0; u < 16; ++u) {
        KD_BODY(Ee0, Ee1, Ee2, Ee3, 2 * u);
        KD_BODY(Eo0, Eo1, Eo2, Eo3, 2 * u + 1);
    }
    KD_BODY(Ee0, Ee1, Ee2, Ee3, 32);
#undef KD_BODY
    float* d0 = Z + (bo * 128 + hh) * 64 + kx0 * 2;
    float* d1 = Z + (bo * 128 + hh + 64) * 64 + kx0 * 2;
    ((float4*)d0)[0] = make_float4(Ee0.x+Eo0.x, Ee0.y+Eo0.y, Ee0.z+Eo0.z, Ee0.w+Eo0.w);
    ((float4*)d0)[1] = make_float4(Ee1.x+Eo1.x, Ee1.y+Eo1.y, Ee1.z+Eo1.z, Ee1.w+Eo1.w);
    ((float4*)d0)[2] = make_float4(Ee2.x+Eo2.x, Ee2.y+Eo2.y, Ee2.z+Eo2.z, Ee2.w+Eo2.w);
    ((float4*)d0)[3] = make_float4(Ee3.x+Eo3.x, Ee3.y+Eo3.y, Ee3.z+Eo3.z, Ee3.w+Eo3.w);
    ((float4*)d1)[0] = make_float4(Ee0.x-Eo0.x, Ee0.y-Eo0.y, Ee0.z-Eo0.z, Ee0.w-Eo0.w);
    ((float4*)d1)[1] = make_float4(Ee1.x-Eo1.x, Ee1.y-Eo1.y, Ee1.z-Eo1.z, Ee1.w-Eo1.w);
    ((float4*)d1)[2] = make_float4(Ee2.x-Eo2.x, Ee2.y-Eo2.y, Ee2.z-Eo2.z, Ee2.w-Eo2.w);
    ((float4*)d1)[3] = make_float4(Ee3.x-Eo3.x, Ee3.y-Eo3.y, Ee3.z-Eo3.z, Ee3.w-Eo3.w);
}

// ---- kE (GEMM-style): Y[h][w] = sum_q Z[h][q]*T[q][w] + bias --------------
__global__ __launch_bounds__(256) void kE(const float* __restrict__ Z,
                                          const float* __restrict__ bias,
                                          float* __restrict__ out) {
    __shared__ float tabs[258];
    __shared__ __align__(16) float Ts[64 * 128];
    __shared__ __align__(16) float Zt[64 * 68];
    build_tab(tabs);
    __syncthreads();
    int t = threadIdx.x;
    int bid = blockIdx.x;
    size_t bo = bid >> 1;
    int hbase = (bid & 1) << 6;
    const float inv = 6.103515625e-05f;  // 1/16384
    #pragma unroll
    for (int i = 0; i < 32; ++i) {
        int e = t + i * 256;
        int q = e >> 7, w = e & 127;
        int k = q >> 1;
        int idx = (k * w) & 127;
        float val;
        if (q == 0)      val = inv;
        else if (q == 1) val = 0.f;
        else if (q & 1)  val = -2.f * inv * tabs[129 + idx];
        else             val =  2.f * inv * tabs[idx];
        Ts[e] = val;
    }
    const float* Zb = Z + (bo * 128 + hbase) * 64;
    #pragma unroll
    for (int s = 0; s < 4; ++s) {
        int u = t + s * 256;
        int h = u & 63, qg = u >> 6;
        float4 v = *(const float4*)(Zb + h * 64 + qg * 4);
        Zt[(qg * 4 + 0) * 68 + h] = v.x;
        Zt[(qg * 4 + 1) * 68 + h] = v.y;
        Zt[(qg * 4 + 2) * 68 + h] = v.z;
        Zt[(qg * 4 + 3) * 68 + h] = v.w;
    }
    __syncthreads();
    int w0 = (t & 31) * 4;
    int h0 = (t >> 5) * 8;
    float4 acc[8];
    #pragma unroll
    for (int j = 0; j < 8; ++j) acc[j] = make_float4(0.f, 0.f, 0.f, 0.f);
    #pragma unroll 2
    for (int q = 0; q < 64; ++q) {
        const float4* zp = (const float4*)(&Zt[q * 68 + h0]);
        float4 z0 = zp[0], z1 = zp[1];
        float4 tw = *(const float4*)(&Ts[q * 128 + w0]);
        acc[0].x = fmaf(z0.x, tw.x, acc[0].x); acc[0].y = fmaf(z0.x, tw.y, acc[0].y);
        acc[0].z = fmaf(z0.x, tw.z, acc[0].z); acc[0].w = fmaf(z0.x, tw.w, acc[0].w);
        acc[1].x = fmaf(z0.y, tw.x, acc[1].x); acc[1].y = fmaf(z0.y, tw.y, acc[1].y);
        acc[1].z = fmaf(z0.y, tw.z, acc[1].z); acc[1].w = fmaf(z0.y, tw.w, acc[1].w);
        acc[2].x = fmaf(z0.z, tw.x, acc[2].x); acc[2].y = fmaf(z0.z, tw.y, acc[2].y);
        acc[2].z = fmaf(z0.z, tw.z, acc[2].z); acc[2].w = fmaf(z0.z, tw.w, acc[2].w);
        acc[3].x = fmaf(z0.w, tw.x, acc[3].x); acc[3].y = fmaf(z0.w, tw.y, acc[3].y);
        acc[3].z = fmaf(z0.w, tw.z, acc[3].z); acc[3].w = fmaf(z0.w, tw.w, acc[3].w);
        acc[4].x = fmaf(z1.x, tw.x, acc[4].x); acc[4].y = fmaf(z1.x, tw.y, acc[4].y);
        acc[4].z = fmaf(z1.x, tw.z, acc[4].z); acc[4].w = fmaf(z1.x, tw.w, acc[4].w);
        acc[5].x = fmaf(z1.y, tw.x, acc[5].x); acc[5].y = fmaf(z1.y, tw.y, acc[5].y);
        acc[5].z = fmaf(z1.y, tw.z, acc[5].z); acc[5].w = fmaf(z1.y, tw.w, acc[5].w);
        acc[6].x = fmaf(z1.z, tw.x, acc[6].x); acc[6].y = fmaf(z1.z, tw.y, acc[6].y);
        acc[6].z = fmaf(z1.z, tw.z, acc[6].z); acc[6].w = fmaf(z1.z, tw.w, acc[6].w);
        acc[7].x = fmaf(z1.w, tw.x, acc[7].x); acc[7].y = fmaf(z1.w, tw.y, acc[7].y);
        acc[7].z = fmaf(z1.w, tw.z, acc[7].z); acc[7].w = fmaf(z1.w, tw.w, acc[7].w);
    }
    float bv = bias[(int)(bo & 63)];
    float* ob = out + ((size_t)(bo * 128 + hbase + h0)) * 128 + w0;
    #pragma unroll
    for (int j = 0; j < 8; ++j) {
        float4 r = acc[j];
        r.x += bv; r.y += bv; r.z += bv; r.w += bv;
        *(float4*)(ob + (size_t)j * 128) = r;
    }
}

extern "C" void kernel_launch(void* const* d_in, const int* in_sizes, int n_in,
                              void* d_out, int out_size, void* d_ws, size_t ws_size,
                              hipStream_t stream) {
    (void)in_sizes; (void)n_in; (void)out_size; (void)ws_size;
    const float* x    = (const float*)d_in[0];
    const float* wgt  = (const float*)d_in[1];
    const float* bias = (const float*)d_in[2];
    float* outp   = (float*)d_out;
    char* ws = (char*)d_ws;
    float* bufXF  = (float*)(ws + (48u << 20));     // [48, 64 MiB)
    float* bufYF0 = (float*)(ws);                   // [0, 16 MiB)
    float* bufYF1 = (float*)(ws + (16u << 20));     // [16, 32 MiB)
    float* bufZ   = (float*)(ws + (32u << 20));     // [32, 64 MiB) (XF dead by kD)
    hipLaunchKernelGGL(kAB, dim3(1024), dim3(256), 0, stream, x, bufXF);
    hipLaunchKernelGGL(kC, dim3(1024), dim3(256), 0, stream, bufXF, wgt, bufYF0, bufYF1);
    hipLaunchKernelGGL(kD, dim3(1024), dim3(256), 0, stream, bufYF0, bufYF1, bufZ);
    hipLaunchKernelGGL(kE, dim3(2048), dim3(256), 0, stream, bufZ, bias, outp);
}

// Round 10
// 138.713 us; speedup vs baseline: 1.1350x; 1.1350x over previous
//
#include <hip/hip_runtime.h>

// FactorizedSpectralConv2d: B=16, CIN=COUT=64, H=W=128, MH=MW=32, super_res=1
// kAB (W-rDFT GEMM + folded H-DFT, async-staged) -> kC (channel mix, W in regs)
// -> kD (inv H-DFT, folded, sums YF0+YF1) -> kE (inv W-rDFT + bias, GEMM).
// ws layout (64 MiB): XF[48,64) ; YF0[0,16) ; YF1[16,32) ; Z[32,64) (XF dead)

__device__ __forceinline__ void build_tab(float* tabs) {
    int t = threadIdx.x;
    if (t < 128) {
        float ang = (float)t * 0.049087385212340517f;  // 2*pi/128
        float s, c;
        sincosf(ang, &s, &c);
        tabs[t] = c;        // cos at [0..127]
        tabs[129 + t] = s;  // sin at [129..256]
    }
}

// ---- kAB: fused W-rDFT (per (b,ci) image) + folded H-DFT ------------------
// Phase 1: A[h][q=2kx+p] = rDFT_W(x)[kx] via LDS GEMM, acc in regs.
//   T14 staging: loads of phase ph+1 issued into regs BEFORE compute(ph),
//   fold+LDS-write after the post-compute barrier.
// Fold in regs -> Af planes in LDS, then kB-part computes XF rows k & 64-k.
__global__ __launch_bounds__(256) void kAB(const float* __restrict__ x,
                                           float* __restrict__ XF) {
    __shared__ float tabs[258];
    __shared__ __align__(16) float smem[8256];  // Twid[0,4096)|xeo[4096,8256); later Af[0,8192)
    build_tab(tabs);
    __syncthreads();
    int t = threadIdx.x;
    size_t bc = blockIdx.x;  // b*64+ci, 1024 blocks
    float* Twid = smem;
    float* xeo  = smem + 4096;
    #pragma unroll
    for (int i = 0; i < 16; ++i) {
        int e = t + i * 256;
        int w = e >> 6, q = e & 63, kx = q >> 1;
        int idx = (w * kx) & 127;
        Twid[e] = (q & 1) ? -tabs[129 + idx] : tabs[idx];
    }
    const float* xb = x + bc * 16384;
    int th = t & 15;
    int tq = t >> 4;
    int q0 = tq * 4;
    int wl4 = (t & 3) * 4;
    int hb  = t >> 2;
    float4 rlo0, rhi0, rlo1, rhi1;
    auto loadR = [&](int ph) {
        rlo0 = *(const float4*)(xb + hb * 128 + ph * 16 + wl4);
        rhi0 = *(const float4*)(xb + hb * 128 + ph * 16 + wl4 + 64);
        rlo1 = *(const float4*)(xb + (64 + hb) * 128 + ph * 16 + wl4);
        rhi1 = *(const float4*)(xb + (64 + hb) * 128 + ph * 16 + wl4 + 64);
    };
    auto writeR = [&]() {
        int h0 = hb, h1 = 64 + hb;
        *(float2*)(&xeo[(wl4+0)*260 + 2*h0]) = make_float2(rlo0.x+rhi0.x, rlo0.x-rhi0.x);
        *(float2*)(&xeo[(wl4+1)*260 + 2*h0]) = make_float2(rlo0.y+rhi0.y, rlo0.y-rhi0.y);
        *(float2*)(&xeo[(wl4+2)*260 + 2*h0]) = make_float2(rlo0.z+rhi0.z, rlo0.z-rhi0.z);
        *(float2*)(&xeo[(wl4+3)*260 + 2*h0]) = make_float2(rlo0.w+rhi0.w, rlo0.w-rhi0.w);
        *(float2*)(&xeo[(wl4+0)*260 + 2*h1]) = make_float2(rlo1.x+rhi1.x, rlo1.x-rhi1.x);
        *(float2*)(&xeo[(wl4+1)*260 + 2*h1]) = make_float2(rlo1.y+rhi1.y, rlo1.y-rhi1.y);
        *(float2*)(&xeo[(wl4+2)*260 + 2*h1]) = make_float2(rlo1.z+rhi1.z, rlo1.z-rhi1.z);
        *(float2*)(&xeo[(wl4+3)*260 + 2*h1]) = make_float2(rlo1.w+rhi1.w, rlo1.w-rhi1.w);
    };
    loadR(0);
    writeR();
    float4 acc8[8];
    #pragma unroll
    for (int j = 0; j < 8; ++j) acc8[j] = make_float4(0.f, 0.f, 0.f, 0.f);
    __syncthreads();  // xeo(0) ready
    for (int ph = 0; ph < 4; ++ph) {
        if (ph < 3) loadR(ph + 1);  // global loads fly under compute
        #pragma unroll 4
        for (int wl = 0; wl < 16; ++wl) {
            int w = ph * 16 + wl;
            float4 tw = *(const float4*)(&Twid[w * 64 + q0]);
            const float* xr = &xeo[wl * 260 + 4 * th];
            #pragma unroll
            for (int i = 0; i < 4; ++i) {
                float4 d = *(const float4*)(xr + 64 * i);
                acc8[2*i].x   = fmaf(d.x, tw.x, acc8[2*i].x);
                acc8[2*i].y   = fmaf(d.x, tw.y, acc8[2*i].y);
                acc8[2*i].z   = fmaf(d.y, tw.z, acc8[2*i].z);
                acc8[2*i].w   = fmaf(d.y, tw.w, acc8[2*i].w);
                acc8[2*i+1].x = fmaf(d.z, tw.x, acc8[2*i+1].x);
                acc8[2*i+1].y = fmaf(d.z, tw.y, acc8[2*i+1].y);
                acc8[2*i+1].z = fmaf(d.w, tw.z, acc8[2*i+1].z);
                acc8[2*i+1].w = fmaf(d.w, tw.w, acc8[2*i+1].w);
            }
        }
        __syncthreads();  // compute(ph) done everywhere -> safe to overwrite xeo
        if (ph < 3) {
            writeR();
            __syncthreads();  // xeo(ph+1) ready
        }
    }
    // In-register fold -> Af planes (overlays Twid/xeo; all reads done).
    float* Af = smem;
    #pragma unroll
    for (int i = 0; i < 2; ++i) {
        int m = 16 * i + th;  // h = 2m (r=0), 2m+1 (r=1)
        float4 a = acc8[2*i],     b = acc8[2*i + 4];
        float4 c = acc8[2*i + 1], d = acc8[2*i + 5];
        *(float4*)(&Af[       m*64 + q0]) = make_float4(a.x+b.x, a.y+b.y, a.z+b.z, a.w+b.w);
        *(float4*)(&Af[2048 + m*64 + q0]) = make_float4(a.x-b.x, a.y-b.y, a.z-b.z, a.w-b.w);
        *(float4*)(&Af[4096 + m*64 + q0]) = make_float4(c.x+d.x, c.y+d.y, c.z+d.z, c.w+d.w);
        *(float4*)(&Af[6144 + m*64 + q0]) = make_float4(c.x-d.x, c.y-d.y, c.z-d.z, c.w-d.w);
    }
    __syncthreads();
    // ---- kB compute part ----
    {
        int k = t & 31, kxg = t >> 5;
        int kx0 = kxg * 4;
        int sig = k & 1;
        const float* pe = Af + sig * 2048;
        const float* po = Af + 4096 + sig * 2048;
        float4 P1 = {0,0,0,0}, P2 = {0,0,0,0}, P3 = {0,0,0,0}, P4 = {0,0,0,0};
        int idx_e = 0;
        for (int m = 0; m < 32; ++m) {
            float ce = tabs[idx_e], se = tabs[129 + idx_e];
            int idx_o = (idx_e + k) & 127;
            float co_ = tabs[idx_o], so_ = tabs[129 + idx_o];
            idx_e = (idx_e + 2 * k) & 127;
            float4 ae01 = *(const float4*)(pe + m * 64 + 2 * kx0);
            float4 ae23 = *(const float4*)(pe + m * 64 + 2 * kx0 + 4);
            float4 ao01 = *(const float4*)(po + m * 64 + 2 * kx0);
            float4 ao23 = *(const float4*)(po + m * 64 + 2 * kx0 + 4);
            P1.x = fmaf(ae01.x, ce, P1.x); P1.x = fmaf(ao01.x, co_, P1.x);
            P2.x = fmaf(ae01.y, se, P2.x); P2.x = fmaf(ao01.y, so_, P2.x);
            P3.x = fmaf(ae01.y, ce, P3.x); P3.x = fmaf(ao01.y, co_, P3.x);
            P4.x = fmaf(ae01.x, se, P4.x); P4.x = fmaf(ao01.x, so_, P4.x);
            P1.y = fmaf(ae01.z, ce, P1.y); P1.y = fmaf(ao01.z, co_, P1.y);
            P2.y = fmaf(ae01.w, se, P2.y); P2.y = fmaf(ao01.w, so_, P2.y);
            P3.y = fmaf(ae01.w, ce, P3.y); P3.y = fmaf(ao01.w, co_, P3.y);
            P4.y = fmaf(ae01.z, se, P4.y); P4.y = fmaf(ao01.z, so_, P4.y);
            P1.z = fmaf(ae23.x, ce, P1.z); P1.z = fmaf(ao23.x, co_, P1.z);
            P2.z = fmaf(ae23.y, se, P2.z); P2.z = fmaf(ao23.y, so_, P2.z);
            P3.z = fmaf(ae23.y, ce, P3.z); P3.z = fmaf(ao23.y, co_, P3.z);
            P4.z = fmaf(ae23.x, se, P4.z); P4.z = fmaf(ao23.x, so_, P4.z);
            P1.w = fmaf(ae23.z, ce, P1.w); P1.w = fmaf(ao23.z, co_, P1.w);
            P2.w = fmaf(ae23.w, se, P2.w); P2.w = fmaf(ao23.w, so_, P2.w);
            P3.w = fmaf(ae23.w, ce, P3.w); P3.w = fmaf(ao23.w, co_, P3.w);
            P4.w = fmaf(ae23.z, se, P4.w); P4.w = fmaf(ao23.z, so_, P4.w);
        }
        float* xfb = XF + bc * 4096;
        *(float4*)(xfb + (k * 32 + kx0) * 2) =
            make_float4(P1.x + P2.x, P3.x - P4.x, P1.y + P2.y, P3.y - P4.y);
        *(float4*)(xfb + (k * 32 + kx0) * 2 + 4) =
            make_float4(P1.z + P2.z, P3.z - P4.z, P1.w + P2.w, P3.w - P4.w);
        if (k) {
            *(float4*)(xfb + ((64 - k) * 32 + kx0) * 2) =
                make_float4(P1.x - P2.x, P3.x + P4.x, P1.y - P2.y, P3.y + P4.y);
            *(float4*)(xfb + ((64 - k) * 32 + kx0) * 2 + 4) =
                make_float4(P1.z - P2.z, P3.z + P4.z, P1.w - P2.w, P3.w + P4.w);
        }
        if (t < 32) {
            int kx = t;
            float re = 0.f, im = 0.f;
            #pragma unroll 8
            for (int m = 0; m < 32; ++m) {
                float2 aep = *(const float2*)(&Af[       m * 64 + 2 * kx]);
                float2 aop = *(const float2*)(&Af[4096 + m * 64 + 2 * kx]);
                float sg = (m & 1) ? -1.f : 1.f;
                re = fmaf(sg, aep.x - aop.y, re);
                im = fmaf(sg, aep.y + aop.x, im);
            }
            xfb[(32 * 32 + kx) * 2]     = re;
            xfb[(32 * 32 + kx) * 2 + 1] = im;
        }
    }
}

// ---- kC v2: channel mix; thread=(co,mx), acc over b; W streams in regs ----
// 1024 blocks = c<<9 | my<<4 | cot<<2 | mxh<<1 | cih. Only X goes through LDS
// (16 KB, T14 double-pumped). W[ci][co][mx] is thread-private: global->reg->fma.
__global__ __launch_bounds__(256, 4) void kC(const float* __restrict__ XF,
                                             const float* __restrict__ Wgt,
                                             float* __restrict__ YF0,
                                             float* __restrict__ YF1) {
    __shared__ float2 Xs[2048];  // [ci_l 8][b 16][mx 16], 16 KB
    int t = threadIdx.x;
    int bid = blockIdx.x;
    int cih = bid & 1;
    int mxh = (bid >> 1) & 1;
    int cot = (bid >> 2) & 3;
    int my  = (bid >> 4) & 31;
    int c   = bid >> 9;
    int co0 = cot * 16;
    int slotbase = (c * 32 + my) * 32 + mxh * 16;
    int mx = t & 15;
    int co_l = t >> 4;
    int co = co0 + co_l;
    int ci0 = cih * 32;
    float2 acc[16];
    #pragma unroll
    for (int i = 0; i < 16; ++i) acc[i] = make_float2(0.f, 0.f);
    // W base for this thread: Wgt[c][ci][co][my][mx], re at +0, im at +2*4096*1024
    const float* wp = Wgt + (size_t)c * 4194304 + (size_t)my * 32 + mxh * 16 + mx
                          + ((size_t)(ci0 * 64) + co) * 1024;
    float2 rw0[8], rw1[8], rx[8];
    auto loadW = [&](int cc, float2* rw) {
        #pragma unroll
        for (int j = 0; j < 8; ++j) {
            size_t off = (size_t)(cc * 8 + j) * 65536;  // 64 g-rows * 1024
            rw[j].x = wp[off];
            rw[j].y = wp[off + 8388608];  // im plane: +2*4096*1024 floats
        }
    };
    auto loadX = [&](int cc) {
        #pragma unroll
        for (int s = 0; s < 8; ++s) {
            int e = t + s * 256;
            int emx = e & 15, eb = (e >> 4) & 15, eci = e >> 8;
            int ci = ci0 + cc * 8 + eci;
            rx[s] = *(const float2*)(XF + ((size_t)(eb * 64 + ci) * 2048 + slotbase + emx) * 2);
        }
    };
    auto writeX = [&]() {
        #pragma unroll
        for (int s = 0; s < 8; ++s) Xs[t + s * 256] = rx[s];
    };
#define KC_COMPUTE(RW)                                                       \
    {                                                                        \
        _Pragma("unroll")                                                    \
        for (int j = 0; j < 8; ++j) {                                        \
            float2 w = RW[j];                                                \
            _Pragma("unroll")                                                \
            for (int b = 0; b < 16; ++b) {                                   \
                float2 xv = Xs[(j * 16 + b) * 16 + mx];                      \
                acc[b].x = fmaf(xv.x, w.x, acc[b].x);                        \
                acc[b].x = fmaf(-xv.y, w.y, acc[b].x);                       \
                acc[b].y = fmaf(xv.x, w.y, acc[b].y);                        \
                acc[b].y = fmaf(xv.y, w.x, acc[b].y);                        \
            }                                                                \
        }                                                                    \
    }
    loadX(0); loadW(0, rw0);
    writeX();
    __syncthreads();
    // cc = 0
    loadX(1); loadW(1, rw1);
    KC_COMPUTE(rw0);
    __syncthreads();
    writeX(); __syncthreads();
    // cc = 1
    loadX(2); loadW(2, rw0);
    KC_COMPUTE(rw1);
    __syncthreads();
    writeX(); __syncthreads();
    // cc = 2
    loadX(3); loadW(3, rw1);
    KC_COMPUTE(rw0);
    __syncthreads();
    writeX(); __syncthreads();
    // cc = 3
    KC_COMPUTE(rw1);
#undef KC_COMPUTE
    float* YF = cih ? YF1 : YF0;
    #pragma unroll
    for (int b = 0; b < 16; ++b) {
        *(float2*)(YF + ((size_t)(b * 64 + co) * 2048 + slotbase + mx) * 2) = acc[b];
    }
}

// ---- kD (folded): Z[h][kx] = Σ_{k=0..32} C_k(h)·Q[k] + i·S_k(h)·R[k] ------
__global__ __launch_bounds__(256) void kD(const float* __restrict__ YF0,
                                          const float* __restrict__ YF1,
                                          float* __restrict__ Z) {
    __shared__ float tabs[258];
    __shared__ __align__(16) float Qs[33 * 64];
    __shared__ __align__(16) float Rs[33 * 64];
    build_tab(tabs);
    int t = threadIdx.x;
    size_t bo = blockIdx.x;
    const float* y0 = YF0 + bo * 4096;
    const float* y1 = YF1 + bo * 4096;
    for (int u = t; u < 528; u += 256) {
        int k = u >> 4, kxf = (u & 15) * 4;
        float4 a0 = *(const float4*)(y0 + k * 64 + kxf);
        float4 a1 = *(const float4*)(y1 + k * 64 + kxf);
        float4 a = make_float4(a0.x+a1.x, a0.y+a1.y, a0.z+a1.z, a0.w+a1.w);
        float4 Q, R;
        if (k == 0) { Q = a; R = make_float4(0.f, 0.f, 0.f, 0.f); }
        else if (k == 32) { Q = a; R = make_float4(-a.x, -a.y, -a.z, -a.w); }
        else {
            float4 b0 = *(const float4*)(y0 + (64 - k) * 64 + kxf);
            float4 b1 = *(const float4*)(y1 + (64 - k) * 64 + kxf);
            float4 bb = make_float4(b0.x+b1.x, b0.y+b1.y, b0.z+b1.z, b0.w+b1.w);
            Q = make_float4(a.x+bb.x, a.y+bb.y, a.z+bb.z, a.w+bb.w);
            R = make_float4(a.x-bb.x, a.y-bb.y, a.z-bb.z, a.w-bb.w);
        }
        *(float4*)(&Qs[k * 64 + kxf]) = Q;
        *(float4*)(&Rs[k * 64 + kxf]) = R;
    }
    __syncthreads();
    int hh = t >> 2;
    int kx0 = (t & 3) * 8;
    float4 Ee0 = {0,0,0,0}, Ee1 = {0,0,0,0}, Ee2 = {0,0,0,0}, Ee3 = {0,0,0,0};
    float4 Eo0 = {0,0,0,0}, Eo1 = {0,0,0,0}, Eo2 = {0,0,0,0}, Eo3 = {0,0,0,0};
    int idx = 0;
#define KD_BODY(E0, E1, E2, E3, kk)                                          \
    {                                                                        \
        float c = tabs[idx], s = tabs[129 + idx];                            \
        const float4* Qp = (const float4*)(&Qs[(kk) * 64 + kx0 * 2]);        \
        const float4* Rp = (const float4*)(&Rs[(kk) * 64 + kx0 * 2]);        \
        float4 Qv, Rv;                                                       \
        Qv = Qp[0]; Rv = Rp[0];                                              \
        E0.x = fmaf(c, Qv.x, E0.x); E0.x = fmaf(-s, Rv.y, E0.x);             \
        E0.y = fmaf(c, Qv.y, E0.y); E0.y = fmaf(s, Rv.x, E0.y);              \
        E0.z = fmaf(c, Qv.z, E0.z); E0.z = fmaf(-s, Rv.w, E0.z);             \
        E0.w = fmaf(c, Qv.w, E0.w); E0.w = fmaf(s, Rv.z, E0.w);              \
        Qv = Qp[1]; Rv = Rp[1];                                              \
        E1.x = fmaf(c, Qv.x, E1.x); E1.x = fmaf(-s, Rv.y, E1.x);             \
        E1.y = fmaf(c, Qv.y, E1.y); E1.y = fmaf(s, Rv.x, E1.y);              \
        E1.z = fmaf(c, Qv.z, E1.z); E1.z = fmaf(-s, Rv.w, E1.z);             \
        E1.w = fmaf(c, Qv.w, E1.w); E1.w = fmaf(s, Rv.z, E1.w);              \
        Qv = Qp[2]; Rv = Rp[2];                                              \
        E2.x = fmaf(c, Qv.x, E2.x); E2.x = fmaf(-s, Rv.y, E2.x);             \
        E2.y = fmaf(c, Qv.y, E2.y); E2.y = fmaf(s, Rv.x, E2.y);              \
        E2.z = fmaf(c, Qv.z, E2.z); E2.z = fmaf(-s, Rv.w, E2.z);             \
        E2.w = fmaf(c, Qv.w, E2.w); E2.w = fmaf(s, Rv.z, E2.w);              \
        Qv = Qp[3]; Rv = Rp[3];                                              \
        E3.x = fmaf(c, Qv.x, E3.x); E3.x = fmaf(-s, Rv.y, E3.x);             \
        E3.y = fmaf(c, Qv.y, E3.y); E3.y = fmaf(s, Rv.x, E3.y);              \
        E3.z = fmaf(c, Qv.z, E3.z); E3.z = fmaf(-s, Rv.w, E3.z);             \
        E3.w = fmaf(c, Qv.w, E3.w); E3.w = fmaf(s, Rv.z, E3.w);              \
        idx = (idx + hh) & 127;                                              \
    }
    for (int u = 0; u < 16; ++u) {
        KD_BODY(Ee0, Ee1, Ee2, Ee3, 2 * u);
        KD_BODY(Eo0, Eo1, Eo2, Eo3, 2 * u + 1);
    }
    KD_BODY(Ee0, Ee1, Ee2, Ee3, 32);
#undef KD_BODY
    float* d0 = Z + (bo * 128 + hh) * 64 + kx0 * 2;
    float* d1 = Z + (bo * 128 + hh + 64) * 64 + kx0 * 2;
    ((float4*)d0)[0] = make_float4(Ee0.x+Eo0.x, Ee0.y+Eo0.y, Ee0.z+Eo0.z, Ee0.w+Eo0.w);
    ((float4*)d0)[1] = make_float4(Ee1.x+Eo1.x, Ee1.y+Eo1.y, Ee1.z+Eo1.z, Ee1.w+Eo1.w);
    ((float4*)d0)[2] = make_float4(Ee2.x+Eo2.x, Ee2.y+Eo2.y, Ee2.z+Eo2.z, Ee2.w+Eo2.w);
    ((float4*)d0)[3] = make_float4(Ee3.x+Eo3.x, Ee3.y+Eo3.y, Ee3.z+Eo3.z, Ee3.w+Eo3.w);
    ((float4*)d1)[0] = make_float4(Ee0.x-Eo0.x, Ee0.y-Eo0.y, Ee0.z-Eo0.z, Ee0.w-Eo0.w);
    ((float4*)d1)[1] = make_float4(Ee1.x-Eo1.x, Ee1.y-Eo1.y, Ee1.z-Eo1.z, Ee1.w-Eo1.w);
    ((float4*)d1)[2] = make_float4(Ee2.x-Eo2.x, Ee2.y-Eo2.y, Ee2.z-Eo2.z, Ee2.w-Eo2.w);
    ((float4*)d1)[3] = make_float4(Ee3.x-Eo3.x, Ee3.y-Eo3.y, Ee3.z-Eo3.z, Ee3.w-Eo3.w);
}

// ---- kE (GEMM-style): Y[h][w] = sum_q Z[h][q]*T[q][w] + bias --------------
__global__ __launch_bounds__(256) void kE(const float* __restrict__ Z,
                                          const float* __restrict__ bias,
                                          float* __restrict__ out) {
    __shared__ float tabs[258];
    __shared__ __align__(16) float Ts[64 * 128];
    __shared__ __align__(16) float Zt[64 * 68];
    build_tab(tabs);
    __syncthreads();
    int t = threadIdx.x;
    int bid = blockIdx.x;
    size_t bo = bid >> 1;
    int hbase = (bid & 1) << 6;
    const float inv = 6.103515625e-05f;  // 1/16384
    #pragma unroll
    for (int i = 0; i < 32; ++i) {
        int e = t + i * 256;
        int q = e >> 7, w = e & 127;
        int k = q >> 1;
        int idx = (k * w) & 127;
        float val;
        if (q == 0)      val = inv;
        else if (q == 1) val = 0.f;
        else if (q & 1)  val = -2.f * inv * tabs[129 + idx];
        else             val =  2.f * inv * tabs[idx];
        Ts[e] = val;
    }
    const float* Zb = Z + (bo * 128 + hbase) * 64;
    #pragma unroll
    for (int s = 0; s < 4; ++s) {
        int u = t + s * 256;
        int h = u & 63, qg = u >> 6;
        float4 v = *(const float4*)(Zb + h * 64 + qg * 4);
        Zt[(qg * 4 + 0) * 68 + h] = v.x;
        Zt[(qg * 4 + 1) * 68 + h] = v.y;
        Zt[(qg * 4 + 2) * 68 + h] = v.z;
        Zt[(qg * 4 + 3) * 68 + h] = v.w;
    }
    __syncthreads();
    int w0 = (t & 31) * 4;
    int h0 = (t >> 5) * 8;
    float4 acc[8];
    #pragma unroll
    for (int j = 0; j < 8; ++j) acc[j] = make_float4(0.f, 0.f, 0.f, 0.f);
    #pragma unroll 2
    for (int q = 0; q < 64; ++q) {
        const float4* zp = (const float4*)(&Zt[q * 68 + h0]);
        float4 z0 = zp[0], z1 = zp[1];
        float4 tw = *(const float4*)(&Ts[q * 128 + w0]);
        acc[0].x = fmaf(z0.x, tw.x, acc[0].x); acc[0].y = fmaf(z0.x, tw.y, acc[0].y);
        acc[0].z = fmaf(z0.x, tw.z, acc[0].z); acc[0].w = fmaf(z0.x, tw.w, acc[0].w);
        acc[1].x = fmaf(z0.y, tw.x, acc[1].x); acc[1].y = fmaf(z0.y, tw.y, acc[1].y);
        acc[1].z = fmaf(z0.y, tw.z, acc[1].z); acc[1].w = fmaf(z0.y, tw.w, acc[1].w);
        acc[2].x = fmaf(z0.z, tw.x, acc[2].x); acc[2].y = fmaf(z0.z, tw.y, acc[2].y);
        acc[2].z = fmaf(z0.z, tw.z, acc[2].z); acc[2].w = fmaf(z0.z, tw.w, acc[2].w);
        acc[3].x = fmaf(z0.w, tw.x, acc[3].x); acc[3].y = fmaf(z0.w, tw.y, acc[3].y);
        acc[3].z = fmaf(z0.w, tw.z, acc[3].z); acc[3].w = fmaf(z0.w, tw.w, acc[3].w);
        acc[4].x = fmaf(z1.x, tw.x, acc[4].x); acc[4].y = fmaf(z1.x, tw.y, acc[4].y);
        acc[4].z = fmaf(z1.x, tw.z, acc[4].z); acc[4].w = fmaf(z1.x, tw.w, acc[4].w);
        acc[5].x = fmaf(z1.y, tw.x, acc[5].x); acc[5].y = fmaf(z1.y, tw.y, acc[5].y);
        acc[5].z = fmaf(z1.y, tw.z, acc[5].z); acc[5].w = fmaf(z1.y, tw.w, acc[5].w);
        acc[6].x = fmaf(z1.z, tw.x, acc[6].x); acc[6].y = fmaf(z1.z, tw.y, acc[6].y);
        acc[6].z = fmaf(z1.z, tw.z, acc[6].z); acc[6].w = fmaf(z1.z, tw.w, acc[6].w);
        acc[7].x = fmaf(z1.w, tw.x, acc[7].x); acc[7].y = fmaf(z1.w, tw.y, acc[7].y);
        acc[7].z = fmaf(z1.w, tw.z, acc[7].z); acc[7].w = fmaf(z1.w, tw.w, acc[7].w);
    }
    float bv = bias[(int)(bo & 63)];
    float* ob = out + ((size_t)(bo * 128 + hbase + h0)) * 128 + w0;
    #pragma unroll
    for (int j = 0; j < 8; ++j) {
        float4 r = acc[j];
        r.x += bv; r.y += bv; r.z += bv; r.w += bv;
        *(float4*)(ob + (size_t)j * 128) = r;
    }
}

extern "C" void kernel_launch(void* const* d_in, const int* in_sizes, int n_in,
                              void* d_out, int out_size, void* d_ws, size_t ws_size,
                              hipStream_t stream) {
    (void)in_sizes; (void)n_in; (void)out_size; (void)ws_size;
    const float* x    = (const float*)d_in[0];
    const float* wgt  = (const float*)d_in[1];
    const float* bias = (const float*)d_in[2];
    float* outp   = (float*)d_out;
    char* ws = (char*)d_ws;
    float* bufXF  = (float*)(ws + (48u << 20));     // [48, 64 MiB)
    float* bufYF0 = (float*)(ws);                   // [0, 16 MiB)
    float* bufYF1 = (float*)(ws + (16u << 20));     // [16, 32 MiB)
    float* bufZ   = (float*)(ws + (32u << 20));     // [32, 64 MiB) (XF dead by kD)
    hipLaunchKernelGGL(kAB, dim3(1024), dim3(256), 0, stream, x, bufXF);
    hipLaunchKernelGGL(kC, dim3(1024), dim3(256), 0, stream, bufXF, wgt, bufYF0, bufYF1);
    hipLaunchKernelGGL(kD, dim3(1024), dim3(256), 0, stream, bufYF0, bufYF1, bufZ);
    hipLaunchKernelGGL(kE, dim3(2048), dim3(256), 0, stream, bufZ, bias, outp);
}

// Round 11
// 132.603 us; speedup vs baseline: 1.1873x; 1.0461x over previous
//
#include <hip/hip_runtime.h>

// FactorizedSpectralConv2d: B=16, CIN=COUT=64, H=W=128, MH=MW=32, super_res=1
// kAB (W-rDFT GEMM + folded H-DFT; 4h x 8q tile, twiddle recurrence, padded Af)
// -> kC (channel mix, W in regs) -> kD (inv H-DFT folded) -> kE (inv W-rDFT).
// ws layout (64 MiB): XF[48,64) ; YF0[0,16) ; YF1[16,32) ; Z[32,64) (XF dead)

__device__ __forceinline__ void build_tab(float* tabs) {
    int t = threadIdx.x;
    if (t < 128) {
        float ang = (float)t * 0.049087385212340517f;  // 2*pi/128
        float s, c;
        sincosf(ang, &s, &c);
        tabs[t] = c;        // cos at [0..127]
        tabs[129 + t] = s;  // sin at [129..256]
    }
}

// ---- kAB: fused W-rDFT (per (b,ci) image) + folded H-DFT ------------------
// Phase 1: A[h][q=2kx+p] via LDS GEMM; thread tile 4h x 8q (2 xeo + 2 Twid
// b128 reads per w -> 32 fma). T14 staging. In-register (h,h+64) fold ->
// 4 Af planes (row stride 68). Phase 2: XF rows k & 64-k; twiddles by
// per-lane complex rotation recurrence (no per-m LDS gathers).
__global__ __launch_bounds__(256) void kAB(const float* __restrict__ x,
                                           float* __restrict__ XF) {
    __shared__ float tabs[258];
    __shared__ __align__(16) float smem[8704];  // Twid[0,4096)|xeo[4096,8256); later Af[0,8704)
    build_tab(tabs);
    __syncthreads();
    int t = threadIdx.x;
    size_t bc = blockIdx.x;  // b*64+ci, 1024 blocks
    float* Twid = smem;
    float* xeo  = smem + 4096;
    #pragma unroll
    for (int i = 0; i < 16; ++i) {
        int e = t + i * 256;
        int w = e >> 6, q = e & 63, kx = q >> 1;
        int idx = (w * kx) & 127;
        Twid[e] = (q & 1) ? -tabs[129 + idx] : tabs[idx];
    }
    const float* xb = x + bc * 16384;
    int th = t & 31;   // h in {2th, 2th+1, 2th+64, 2th+65}
    int tq = t >> 5;   // q in [8tq, 8tq+8), kx in [4tq, 4tq+4)
    int q0 = tq * 8;
    int wl4 = (t & 3) * 4;  // staging lanes
    int hb  = t >> 2;
    float4 rlo0, rhi0, rlo1, rhi1;
    auto loadR = [&](int ph) {
        rlo0 = *(const float4*)(xb + hb * 128 + ph * 16 + wl4);
        rhi0 = *(const float4*)(xb + hb * 128 + ph * 16 + wl4 + 64);
        rlo1 = *(const float4*)(xb + (64 + hb) * 128 + ph * 16 + wl4);
        rhi1 = *(const float4*)(xb + (64 + hb) * 128 + ph * 16 + wl4 + 64);
    };
    auto writeR = [&]() {
        int h0 = hb, h1 = 64 + hb;
        *(float2*)(&xeo[(wl4+0)*260 + 2*h0]) = make_float2(rlo0.x+rhi0.x, rlo0.x-rhi0.x);
        *(float2*)(&xeo[(wl4+1)*260 + 2*h0]) = make_float2(rlo0.y+rhi0.y, rlo0.y-rhi0.y);
        *(float2*)(&xeo[(wl4+2)*260 + 2*h0]) = make_float2(rlo0.z+rhi0.z, rlo0.z-rhi0.z);
        *(float2*)(&xeo[(wl4+3)*260 + 2*h0]) = make_float2(rlo0.w+rhi0.w, rlo0.w-rhi0.w);
        *(float2*)(&xeo[(wl4+0)*260 + 2*h1]) = make_float2(rlo1.x+rhi1.x, rlo1.x-rhi1.x);
        *(float2*)(&xeo[(wl4+1)*260 + 2*h1]) = make_float2(rlo1.y+rhi1.y, rlo1.y-rhi1.y);
        *(float2*)(&xeo[(wl4+2)*260 + 2*h1]) = make_float2(rlo1.z+rhi1.z, rlo1.z-rhi1.z);
        *(float2*)(&xeo[(wl4+3)*260 + 2*h1]) = make_float2(rlo1.w+rhi1.w, rlo1.w-rhi1.w);
    };
    loadR(0);
    writeR();
    float4 acc[8];
    #pragma unroll
    for (int j = 0; j < 8; ++j) acc[j] = make_float4(0.f, 0.f, 0.f, 0.f);
    __syncthreads();  // xeo(0) ready
    for (int ph = 0; ph < 4; ++ph) {
        if (ph < 3) loadR(ph + 1);  // loads fly under compute
        #pragma unroll 4
        for (int wl = 0; wl < 16; ++wl) {
            int w = ph * 16 + wl;
            const float* xr = &xeo[wl * 260 + 4 * th];
            float4 d0  = *(const float4*)(xr);         // ve,vo for h=2th, 2th+1
            float4 d1  = *(const float4*)(xr + 128);   // ve,vo for h+64
            float4 tw0 = *(const float4*)(&Twid[w * 64 + q0]);
            float4 tw1 = *(const float4*)(&Twid[w * 64 + q0 + 4]);
            acc[0].x = fmaf(d0.x, tw0.x, acc[0].x); acc[0].y = fmaf(d0.x, tw0.y, acc[0].y);
            acc[0].z = fmaf(d0.y, tw0.z, acc[0].z); acc[0].w = fmaf(d0.y, tw0.w, acc[0].w);
            acc[1].x = fmaf(d0.x, tw1.x, acc[1].x); acc[1].y = fmaf(d0.x, tw1.y, acc[1].y);
            acc[1].z = fmaf(d0.y, tw1.z, acc[1].z); acc[1].w = fmaf(d0.y, tw1.w, acc[1].w);
            acc[2].x = fmaf(d0.z, tw0.x, acc[2].x); acc[2].y = fmaf(d0.z, tw0.y, acc[2].y);
            acc[2].z = fmaf(d0.w, tw0.z, acc[2].z); acc[2].w = fmaf(d0.w, tw0.w, acc[2].w);
            acc[3].x = fmaf(d0.z, tw1.x, acc[3].x); acc[3].y = fmaf(d0.z, tw1.y, acc[3].y);
            acc[3].z = fmaf(d0.w, tw1.z, acc[3].z); acc[3].w = fmaf(d0.w, tw1.w, acc[3].w);
            acc[4].x = fmaf(d1.x, tw0.x, acc[4].x); acc[4].y = fmaf(d1.x, tw0.y, acc[4].y);
            acc[4].z = fmaf(d1.y, tw0.z, acc[4].z); acc[4].w = fmaf(d1.y, tw0.w, acc[4].w);
            acc[5].x = fmaf(d1.x, tw1.x, acc[5].x); acc[5].y = fmaf(d1.x, tw1.y, acc[5].y);
            acc[5].z = fmaf(d1.y, tw1.z, acc[5].z); acc[5].w = fmaf(d1.y, tw1.w, acc[5].w);
            acc[6].x = fmaf(d1.z, tw0.x, acc[6].x); acc[6].y = fmaf(d1.z, tw0.y, acc[6].y);
            acc[6].z = fmaf(d1.w, tw0.z, acc[6].z); acc[6].w = fmaf(d1.w, tw0.w, acc[6].w);
            acc[7].x = fmaf(d1.z, tw1.x, acc[7].x); acc[7].y = fmaf(d1.z, tw1.y, acc[7].y);
            acc[7].z = fmaf(d1.w, tw1.z, acc[7].z); acc[7].w = fmaf(d1.w, tw1.w, acc[7].w);
        }
        __syncthreads();  // compute(ph) done -> safe to overwrite xeo
        if (ph < 3) {
            writeR();
            __syncthreads();  // xeo(ph+1) ready
        }
    }
    // In-register (h, h+64) fold -> Af planes, row stride 68 (bank spread).
    // even rows (h=2th -> m=th): planes 0 (+), 1 (-); odd rows: planes 2, 3.
    float* Af = smem;
    {
        int base = th * 68 + q0;
        *(float4*)(&Af[base])          = make_float4(acc[0].x+acc[4].x, acc[0].y+acc[4].y, acc[0].z+acc[4].z, acc[0].w+acc[4].w);
        *(float4*)(&Af[base + 4])      = make_float4(acc[1].x+acc[5].x, acc[1].y+acc[5].y, acc[1].z+acc[5].z, acc[1].w+acc[5].w);
        *(float4*)(&Af[2176 + base])   = make_float4(acc[0].x-acc[4].x, acc[0].y-acc[4].y, acc[0].z-acc[4].z, acc[0].w-acc[4].w);
        *(float4*)(&Af[2176 + base+4]) = make_float4(acc[1].x-acc[5].x, acc[1].y-acc[5].y, acc[1].z-acc[5].z, acc[1].w-acc[5].w);
        *(float4*)(&Af[4352 + base])   = make_float4(acc[2].x+acc[6].x, acc[2].y+acc[6].y, acc[2].z+acc[6].z, acc[2].w+acc[6].w);
        *(float4*)(&Af[4352 + base+4]) = make_float4(acc[3].x+acc[7].x, acc[3].y+acc[7].y, acc[3].z+acc[7].z, acc[3].w+acc[7].w);
        *(float4*)(&Af[6528 + base])   = make_float4(acc[2].x-acc[6].x, acc[2].y-acc[6].y, acc[2].z-acc[6].z, acc[2].w-acc[6].w);
        *(float4*)(&Af[6528 + base+4]) = make_float4(acc[3].x-acc[7].x, acc[3].y-acc[7].y, acc[3].z-acc[7].z, acc[3].w-acc[7].w);
    }
    __syncthreads();
    // ---- kB compute part (twiddles via rotation recurrence) ----
    {
        int k = t & 31, kxg = t >> 5;
        int kx0 = kxg * 4;
        int sig = k & 1;
        const float* pe = Af + sig * 2176;          // even-h planes (+/-)
        const float* po = Af + 4352 + sig * 2176;   // odd-h planes (+/-)
        int a2 = (2 * k) & 127;
        float ca = tabs[a2], sa = tabs[129 + a2];   // rotation step e^{i*2k*2pi/128}
        float ce = 1.f, se = 0.f;                   // angle 2k*m, m=0
        float co_ = tabs[k], so_ = tabs[129 + k];   // angle 2k*m + k, m=0
        float4 P1 = {0,0,0,0}, P2 = {0,0,0,0}, P3 = {0,0,0,0}, P4 = {0,0,0,0};
        for (int m = 0; m < 32; ++m) {
            float4 ae01 = *(const float4*)(pe + m * 68 + 2 * kx0);
            float4 ae23 = *(const float4*)(pe + m * 68 + 2 * kx0 + 4);
            float4 ao01 = *(const float4*)(po + m * 68 + 2 * kx0);
            float4 ao23 = *(const float4*)(po + m * 68 + 2 * kx0 + 4);
            P1.x = fmaf(ae01.x, ce, P1.x); P1.x = fmaf(ao01.x, co_, P1.x);
            P2.x = fmaf(ae01.y, se, P2.x); P2.x = fmaf(ao01.y, so_, P2.x);
            P3.x = fmaf(ae01.y, ce, P3.x); P3.x = fmaf(ao01.y, co_, P3.x);
            P4.x = fmaf(ae01.x, se, P4.x); P4.x = fmaf(ao01.x, so_, P4.x);
            P1.y = fmaf(ae01.z, ce, P1.y); P1.y = fmaf(ao01.z, co_, P1.y);
            P2.y = fmaf(ae01.w, se, P2.y); P2.y = fmaf(ao01.w, so_, P2.y);
            P3.y = fmaf(ae01.w, ce, P3.y); P3.y = fmaf(ao01.w, co_, P3.y);
            P4.y = fmaf(ae01.z, se, P4.y); P4.y = fmaf(ao01.z, so_, P4.y);
            P1.z = fmaf(ae23.x, ce, P1.z); P1.z = fmaf(ao23.x, co_, P1.z);
            P2.z = fmaf(ae23.y, se, P2.z); P2.z = fmaf(ao23.y, so_, P2.z);
            P3.z = fmaf(ae23.y, ce, P3.z); P3.z = fmaf(ao23.y, co_, P3.z);
            P4.z = fmaf(ae23.x, se, P4.z); P4.z = fmaf(ao23.x, so_, P4.z);
            P1.w = fmaf(ae23.z, ce, P1.w); P1.w = fmaf(ao23.z, co_, P1.w);
            P2.w = fmaf(ae23.w, se, P2.w); P2.w = fmaf(ao23.w, so_, P2.w);
            P3.w = fmaf(ae23.w, ce, P3.w); P3.w = fmaf(ao23.w, co_, P3.w);
            P4.w = fmaf(ae23.z, se, P4.w); P4.w = fmaf(ao23.z, so_, P4.w);
            // rotate both twiddle pairs by (ca, sa)
            float t1 = se * sa, t2 = ce * sa;
            float cen = fmaf(ce, ca, -t1);
            float sen = fmaf(se, ca, t2);
            ce = cen; se = sen;
            float t3 = so_ * sa, t4 = co_ * sa;
            float con = fmaf(co_, ca, -t3);
            float son = fmaf(so_, ca, t4);
            co_ = con; so_ = son;
        }
        float* xfb = XF + bc * 4096;
        *(float4*)(xfb + (k * 32 + kx0) * 2) =
            make_float4(P1.x + P2.x, P3.x - P4.x, P1.y + P2.y, P3.y - P4.y);
        *(float4*)(xfb + (k * 32 + kx0) * 2 + 4) =
            make_float4(P1.z + P2.z, P3.z - P4.z, P1.w + P2.w, P3.w - P4.w);
        if (k) {
            *(float4*)(xfb + ((64 - k) * 32 + kx0) * 2) =
                make_float4(P1.x - P2.x, P3.x + P4.x, P1.y - P2.y, P3.y + P4.y);
            *(float4*)(xfb + ((64 - k) * 32 + kx0) * 2 + 4) =
                make_float4(P1.z - P2.z, P3.z + P4.z, P1.w - P2.w, P3.w + P4.w);
        }
        if (t < 32) {
            int kx = t;
            float re = 0.f, im = 0.f;
            #pragma unroll 8
            for (int m = 0; m < 32; ++m) {
                float2 aep = *(const float2*)(&Af[       m * 68 + 2 * kx]);
                float2 aop = *(const float2*)(&Af[4352 + m * 68 + 2 * kx]);
                float sg = (m & 1) ? -1.f : 1.f;
                re = fmaf(sg, aep.x - aop.y, re);
                im = fmaf(sg, aep.y + aop.x, im);
            }
            xfb[(32 * 32 + kx) * 2]     = re;
            xfb[(32 * 32 + kx) * 2 + 1] = im;
        }
    }
}

// ---- kC v2: channel mix; thread=(co,mx), acc over b; W streams in regs ----
__global__ __launch_bounds__(256, 4) void kC(const float* __restrict__ XF,
                                             const float* __restrict__ Wgt,
                                             float* __restrict__ YF0,
                                             float* __restrict__ YF1) {
    __shared__ float2 Xs[2048];  // [ci_l 8][b 16][mx 16], 16 KB
    int t = threadIdx.x;
    int bid = blockIdx.x;
    int cih = bid & 1;
    int mxh = (bid >> 1) & 1;
    int cot = (bid >> 2) & 3;
    int my  = (bid >> 4) & 31;
    int c   = bid >> 9;
    int co0 = cot * 16;
    int slotbase = (c * 32 + my) * 32 + mxh * 16;
    int mx = t & 15;
    int co_l = t >> 4;
    int co = co0 + co_l;
    int ci0 = cih * 32;
    float2 acc[16];
    #pragma unroll
    for (int i = 0; i < 16; ++i) acc[i] = make_float2(0.f, 0.f);
    const float* wp = Wgt + (size_t)c * 4194304 + (size_t)my * 32 + mxh * 16 + mx
                          + ((size_t)(ci0 * 64) + co) * 1024;
    float2 rw0[8], rw1[8], rx[8];
    auto loadW = [&](int cc, float2* rw) {
        #pragma unroll
        for (int j = 0; j < 8; ++j) {
            size_t off = (size_t)(cc * 8 + j) * 65536;
            rw[j].x = wp[off];
            rw[j].y = wp[off + 8388608];
        }
    };
    auto loadX = [&](int cc) {
        #pragma unroll
        for (int s = 0; s < 8; ++s) {
            int e = t + s * 256;
            int emx = e & 15, eb = (e >> 4) & 15, eci = e >> 8;
            int ci = ci0 + cc * 8 + eci;
            rx[s] = *(const float2*)(XF + ((size_t)(eb * 64 + ci) * 2048 + slotbase + emx) * 2);
        }
    };
    auto writeX = [&]() {
        #pragma unroll
        for (int s = 0; s < 8; ++s) Xs[t + s * 256] = rx[s];
    };
#define KC_COMPUTE(RW)                                                       \
    {                                                                        \
        _Pragma("unroll")                                                    \
        for (int j = 0; j < 8; ++j) {                                        \
            float2 w = RW[j];                                                \
            _Pragma("unroll")                                                \
            for (int b = 0; b < 16; ++b) {                                   \
                float2 xv = Xs[(j * 16 + b) * 16 + mx];                      \
                acc[b].x = fmaf(xv.x, w.x, acc[b].x);                        \
                acc[b].x = fmaf(-xv.y, w.y, acc[b].x);                       \
                acc[b].y = fmaf(xv.x, w.y, acc[b].y);                        \
                acc[b].y = fmaf(xv.y, w.x, acc[b].y);                        \
            }                                                                \
        }                                                                    \
    }
    loadX(0); loadW(0, rw0);
    writeX();
    __syncthreads();
    loadX(1); loadW(1, rw1);
    KC_COMPUTE(rw0);
    __syncthreads();
    writeX(); __syncthreads();
    loadX(2); loadW(2, rw0);
    KC_COMPUTE(rw1);
    __syncthreads();
    writeX(); __syncthreads();
    loadX(3); loadW(3, rw1);
    KC_COMPUTE(rw0);
    __syncthreads();
    writeX(); __syncthreads();
    KC_COMPUTE(rw1);
#undef KC_COMPUTE
    float* YF = cih ? YF1 : YF0;
    #pragma unroll
    for (int b = 0; b < 16; ++b) {
        *(float2*)(YF + ((size_t)(b * 64 + co) * 2048 + slotbase + mx) * 2) = acc[b];
    }
}

// ---- kD (folded): Z[h][kx] = Σ_{k=0..32} C_k(h)·Q[k] + i·S_k(h)·R[k] ------
__global__ __launch_bounds__(256) void kD(const float* __restrict__ YF0,
                                          const float* __restrict__ YF1,
                                          float* __restrict__ Z) {
    __shared__ float tabs[258];
    __shared__ __align__(16) float Qs[33 * 64];
    __shared__ __align__(16) float Rs[33 * 64];
    build_tab(tabs);
    int t = threadIdx.x;
    size_t bo = blockIdx.x;
    const float* y0 = YF0 + bo * 4096;
    const float* y1 = YF1 + bo * 4096;
    for (int u = t; u < 528; u += 256) {
        int k = u >> 4, kxf = (u & 15) * 4;
        float4 a0 = *(const float4*)(y0 + k * 64 + kxf);
        float4 a1 = *(const float4*)(y1 + k * 64 + kxf);
        float4 a = make_float4(a0.x+a1.x, a0.y+a1.y, a0.z+a1.z, a0.w+a1.w);
        float4 Q, R;
        if (k == 0) { Q = a; R = make_float4(0.f, 0.f, 0.f, 0.f); }
        else if (k == 32) { Q = a; R = make_float4(-a.x, -a.y, -a.z, -a.w); }
        else {
            float4 b0 = *(const float4*)(y0 + (64 - k) * 64 + kxf);
            float4 b1 = *(const float4*)(y1 + (64 - k) * 64 + kxf);
            float4 bb = make_float4(b0.x+b1.x, b0.y+b1.y, b0.z+b1.z, b0.w+b1.w);
            Q = make_float4(a.x+bb.x, a.y+bb.y, a.z+bb.z, a.w+bb.w);
            R = make_float4(a.x-bb.x, a.y-bb.y, a.z-bb.z, a.w-bb.w);
        }
        *(float4*)(&Qs[k * 64 + kxf]) = Q;
        *(float4*)(&Rs[k * 64 + kxf]) = R;
    }
    __syncthreads();
    int hh = t >> 2;
    int kx0 = (t & 3) * 8;
    float4 Ee0 = {0,0,0,0}, Ee1 = {0,0,0,0}, Ee2 = {0,0,0,0}, Ee3 = {0,0,0,0};
    float4 Eo0 = {0,0,0,0}, Eo1 = {0,0,0,0}, Eo2 = {0,0,0,0}, Eo3 = {0,0,0,0};
    int idx = 0;
#define KD_BODY(E0, E1, E2, E3, kk)                                          \
    {                                                                        \
        float c = tabs[idx], s = tabs[129 + idx];                            \
        const float4* Qp = (const float4*)(&Qs[(kk) * 64 + kx0 * 2]);        \
        const float4* Rp = (const float4*)(&Rs[(kk) * 64 + kx0 * 2]);        \
        float4 Qv, Rv;                                                       \
        Qv = Qp[0]; Rv = Rp[0];                                              \
        E0.x = fmaf(c, Qv.x, E0.x); E0.x = fmaf(-s, Rv.y, E0.x);             \
        E0.y = fmaf(c, Qv.y, E0.y); E0.y = fmaf(s, Rv.x, E0.y);              \
        E0.z = fmaf(c, Qv.z, E0.z); E0.z = fmaf(-s, Rv.w, E0.z);             \
        E0.w = fmaf(c, Qv.w, E0.w); E0.w = fmaf(s, Rv.z, E0.w);              \
        Qv = Qp[1]; Rv = Rp[1];                                              \
        E1.x = fmaf(c, Qv.x, E1.x); E1.x = fmaf(-s, Rv.y, E1.x);             \
        E1.y = fmaf(c, Qv.y, E1.y); E1.y = fmaf(s, Rv.x, E1.y);              \
        E1.z = fmaf(c, Qv.z, E1.z); E1.z = fmaf(-s, Rv.w, E1.z);             \
        E1.w = fmaf(c, Qv.w, E1.w); E1.w = fmaf(s, Rv.z, E1.w);              \
        Qv = Qp[2]; Rv = Rp[2];                                              \
        E2.x = fmaf(c, Qv.x, E2.x); E2.x = fmaf(-s, Rv.y, E2.x);             \
        E2.y = fmaf(c, Qv.y, E2.y); E2.y = fmaf(s, Rv.x, E2.y);              \
        E2.z = fmaf(c, Qv.z, E2.z); E2.z = fmaf(-s, Rv.w, E2.z);             \
        E2.w = fmaf(c, Qv.w, E2.w); E2.w = fmaf(s, Rv.z, E2.w);              \
        Qv = Qp[3]; Rv = Rp[3];                                              \
        E3.x = fmaf(c, Qv.x, E3.x); E3.x = fmaf(-s, Rv.y, E3.x);             \
        E3.y = fmaf(c, Qv.y, E3.y); E3.y = fmaf(s, Rv.x, E3.y);              \
        E3.z = fmaf(c, Qv.z, E3.z); E3.z = fmaf(-s, Rv.w, E3.z);             \
        E3.w = fmaf(c, Qv.w, E3.w); E3.w = fmaf(s, Rv.z, E3.w);              \
        idx = (idx + hh) & 127;                                              \
    }
    for (int u = 0; u < 16; ++u) {
        KD_BODY(Ee0, Ee1, Ee2, Ee3, 2 * u);
        KD_BODY(Eo0, Eo1, Eo2, Eo3, 2 * u + 1);
    }
    KD_BODY(Ee0, Ee1, Ee2, Ee3, 32);
#undef KD_BODY
    float* d0 = Z + (bo * 128 + hh) * 64 + kx0 * 2;
    float* d1 = Z + (bo * 128 + hh + 64) * 64 + kx0 * 2;
    ((float4*)d0)[0] = make_float4(Ee0.x+Eo0.x, Ee0.y+Eo0.y, Ee0.z+Eo0.z, Ee0.w+Eo0.w);
    ((float4*)d0)[1] = make_float4(Ee1.x+Eo1.x, Ee1.y+Eo1.y, Ee1.z+Eo1.z, Ee1.w+Eo1.w);
    ((float4*)d0)[2] = make_float4(Ee2.x+Eo2.x, Ee2.y+Eo2.y, Ee2.z+Eo2.z, Ee2.w+Eo2.w);
    ((float4*)d0)[3] = make_float4(Ee3.x+Eo3.x, Ee3.y+Eo3.y, Ee3.z+Eo3.z, Ee3.w+Eo3.w);
    ((float4*)d1)[0] = make_float4(Ee0.x-Eo0.x, Ee0.y-Eo0.y, Ee0.z-Eo0.z, Ee0.w-Eo0.w);
    ((float4*)d1)[1] = make_float4(Ee1.x-Eo1.x, Ee1.y-Eo1.y, Ee1.z-Eo1.z, Ee1.w-Eo1.w);
    ((float4*)d1)[2] = make_float4(Ee2.x-Eo2.x, Ee2.y-Eo2.y, Ee2.z-Eo2.z, Ee2.w-Eo2.w);
    ((float4*)d1)[3] = make_float4(Ee3.x-Eo3.x, Ee3.y-Eo3.y, Ee3.z-Eo3.z, Ee3.w-Eo3.w);
}

// ---- kE (GEMM-style): Y[h][w] = sum_q Z[h][q]*T[q][w] + bias --------------
__global__ __launch_bounds__(256) void kE(const float* __restrict__ Z,
                                          const float* __restrict__ bias,
                                          float* __restrict__ out) {
    __shared__ float tabs[258];
    __shared__ __align__(16) float Ts[64 * 128];
    __shared__ __align__(16) float Zt[64 * 68];
    build_tab(tabs);
    __syncthreads();
    int t = threadIdx.x;
    int bid = blockIdx.x;
    size_t bo = bid >> 1;
    int hbase = (bid & 1) << 6;
    const float inv = 6.103515625e-05f;  // 1/16384
    #pragma unroll
    for (int i = 0; i < 32; ++i) {
        int e = t + i * 256;
        int q = e >> 7, w = e & 127;
        int k = q >> 1;
        int idx = (k * w) & 127;
        float val;
        if (q == 0)      val = inv;
        else if (q == 1) val = 0.f;
        else if (q & 1)  val = -2.f * inv * tabs[129 + idx];
        else             val =  2.f * inv * tabs[idx];
        Ts[e] = val;
    }
    const float* Zb = Z + (bo * 128 + hbase) * 64;
    #pragma unroll
    for (int s = 0; s < 4; ++s) {
        int u = t + s * 256;
        int h = u & 63, qg = u >> 6;
        float4 v = *(const float4*)(Zb + h * 64 + qg * 4);
        Zt[(qg * 4 + 0) * 68 + h] = v.x;
        Zt[(qg * 4 + 1) * 68 + h] = v.y;
        Zt[(qg * 4 + 2) * 68 + h] = v.z;
        Zt[(qg * 4 + 3) * 68 + h] = v.w;
    }
    __syncthreads();
    int w0 = (t & 31) * 4;
    int h0 = (t >> 5) * 8;
    float4 acc[8];
    #pragma unroll
    for (int j = 0; j < 8; ++j) acc[j] = make_float4(0.f, 0.f, 0.f, 0.f);
    #pragma unroll 2
    for (int q = 0; q < 64; ++q) {
        const float4* zp = (const float4*)(&Zt[q * 68 + h0]);
        float4 z0 = zp[0], z1 = zp[1];
        float4 tw = *(const float4*)(&Ts[q * 128 + w0]);
        acc[0].x = fmaf(z0.x, tw.x, acc[0].x); acc[0].y = fmaf(z0.x, tw.y, acc[0].y);
        acc[0].z = fmaf(z0.x, tw.z, acc[0].z); acc[0].w = fmaf(z0.x, tw.w, acc[0].w);
        acc[1].x = fmaf(z0.y, tw.x, acc[1].x); acc[1].y = fmaf(z0.y, tw.y, acc[1].y);
        acc[1].z = fmaf(z0.y, tw.z, acc[1].z); acc[1].w = fmaf(z0.y, tw.w, acc[1].w);
        acc[2].x = fmaf(z0.z, tw.x, acc[2].x); acc[2].y = fmaf(z0.z, tw.y, acc[2].y);
        acc[2].z = fmaf(z0.z, tw.z, acc[2].z); acc[2].w = fmaf(z0.z, tw.w, acc[2].w);
        acc[3].x = fmaf(z0.w, tw.x, acc[3].x); acc[3].y = fmaf(z0.w, tw.y, acc[3].y);
        acc[3].z = fmaf(z0.w, tw.z, acc[3].z); acc[3].w = fmaf(z0.w, tw.w, acc[3].w);
        acc[4].x = fmaf(z1.x, tw.x, acc[4].x); acc[4].y = fmaf(z1.x, tw.y, acc[4].y);
        acc[4].z = fmaf(z1.x, tw.z, acc[4].z); acc[4].w = fmaf(z1.x, tw.w, acc[4].w);
        acc[5].x = fmaf(z1.y, tw.x, acc[5].x); acc[5].y = fmaf(z1.y, tw.y, acc[5].y);
        acc[5].z = fmaf(z1.y, tw.z, acc[5].z); acc[5].w = fmaf(z1.y, tw.w, acc[5].w);
        acc[6].x = fmaf(z1.z, tw.x, acc[6].x); acc[6].y = fmaf(z1.z, tw.y, acc[6].y);
        acc[6].z = fmaf(z1.z, tw.z, acc[6].z); acc[6].w = fmaf(z1.z, tw.w, acc[6].w);
        acc[7].x = fmaf(z1.w, tw.x, acc[7].x); acc[7].y = fmaf(z1.w, tw.y, acc[7].y);
        acc[7].z = fmaf(z1.w, tw.z, acc[7].z); acc[7].w = fmaf(z1.w, tw.w, acc[7].w);
    }
    float bv = bias[(int)(bo & 63)];
    float* ob = out + ((size_t)(bo * 128 + hbase + h0)) * 128 + w0;
    #pragma unroll
    for (int j = 0; j < 8; ++j) {
        float4 r = acc[j];
        r.x += bv; r.y += bv; r.z += bv; r.w += bv;
        *(float4*)(ob + (size_t)j * 128) = r;
    }
}

extern "C" void kernel_launch(void* const* d_in, const int* in_sizes, int n_in,
                              void* d_out, int out_size, void* d_ws, size_t ws_size,
                              hipStream_t stream) {
    (void)in_sizes; (void)n_in; (void)out_size; (void)ws_size;
    const float* x    = (const float*)d_in[0];
    const float* wgt  = (const float*)d_in[1];
    const float* bias = (const float*)d_in[2];
    float* outp   = (float*)d_out;
    char* ws = (char*)d_ws;
    float* bufXF  = (float*)(ws + (48u << 20));     // [48, 64 MiB)
    float* bufYF0 = (float*)(ws);                   // [0, 16 MiB)
    float* bufYF1 = (float*)(ws + (16u << 20));     // [16, 32 MiB)
    float* bufZ   = (float*)(ws + (32u << 20));     // [32, 64 MiB) (XF dead by kD)
    hipLaunchKernelGGL(kAB, dim3(1024), dim3(256), 0, stream, x, bufXF);
    hipLaunchKernelGGL(kC, dim3(1024), dim3(256), 0, stream, bufXF, wgt, bufYF0, bufYF1);
    hipLaunchKernelGGL(kD, dim3(1024), dim3(256), 0, stream, bufYF0, bufYF1, bufZ);
    hipLaunchKernelGGL(kE, dim3(2048), dim3(256), 0, stream, bufZ, bias, outp);
}

// Round 12
// 123.346 us; speedup vs baseline: 1.2764x; 1.0751x over previous
//
#include <hip/hip_runtime.h>

// FactorizedSpectralConv2d: B=16, CIN=COUT=64, H=W=128, MH=MW=32, super_res=1
// kAB (W-rDFT GEMM + folded H-DFT) -> kC (channel mix, deep W-prefetch)
// -> kDE (inv H-DFT folded + inv W-rDFT + bias, fused via LDS transpose).
// ws layout (64 MiB): XF[48,64) ; YF0[0,16) ; YF1[16,32)

__device__ __forceinline__ void build_tab(float* tabs) {
    int t = threadIdx.x;
    if (t < 128) {
        float ang = (float)t * 0.049087385212340517f;  // 2*pi/128
        float s, c;
        sincosf(ang, &s, &c);
        tabs[t] = c;        // cos at [0..127]
        tabs[129 + t] = s;  // sin at [129..256]
    }
}

// ---- kAB: fused W-rDFT (per (b,ci) image) + folded H-DFT ------------------
__global__ __launch_bounds__(256) void kAB(const float* __restrict__ x,
                                           float* __restrict__ XF) {
    __shared__ float tabs[258];
    __shared__ __align__(16) float smem[8704];  // Twid[0,4096)|xeo[4096,8256); later Af[0,8704)
    build_tab(tabs);
    __syncthreads();
    int t = threadIdx.x;
    size_t bc = blockIdx.x;  // b*64+ci, 1024 blocks
    float* Twid = smem;
    float* xeo  = smem + 4096;
    #pragma unroll
    for (int i = 0; i < 16; ++i) {
        int e = t + i * 256;
        int w = e >> 6, q = e & 63, kx = q >> 1;
        int idx = (w * kx) & 127;
        Twid[e] = (q & 1) ? -tabs[129 + idx] : tabs[idx];
    }
    const float* xb = x + bc * 16384;
    int th = t & 31;   // h in {2th, 2th+1, 2th+64, 2th+65}
    int tq = t >> 5;   // q in [8tq, 8tq+8)
    int q0 = tq * 8;
    int wl4 = (t & 3) * 4;  // staging lanes
    int hb  = t >> 2;
    float4 rlo0, rhi0, rlo1, rhi1;
    auto loadR = [&](int ph) {
        rlo0 = *(const float4*)(xb + hb * 128 + ph * 16 + wl4);
        rhi0 = *(const float4*)(xb + hb * 128 + ph * 16 + wl4 + 64);
        rlo1 = *(const float4*)(xb + (64 + hb) * 128 + ph * 16 + wl4);
        rhi1 = *(const float4*)(xb + (64 + hb) * 128 + ph * 16 + wl4 + 64);
    };
    auto writeR = [&]() {
        int h0 = hb, h1 = 64 + hb;
        *(float2*)(&xeo[(wl4+0)*260 + 2*h0]) = make_float2(rlo0.x+rhi0.x, rlo0.x-rhi0.x);
        *(float2*)(&xeo[(wl4+1)*260 + 2*h0]) = make_float2(rlo0.y+rhi0.y, rlo0.y-rhi0.y);
        *(float2*)(&xeo[(wl4+2)*260 + 2*h0]) = make_float2(rlo0.z+rhi0.z, rlo0.z-rhi0.z);
        *(float2*)(&xeo[(wl4+3)*260 + 2*h0]) = make_float2(rlo0.w+rhi0.w, rlo0.w-rhi0.w);
        *(float2*)(&xeo[(wl4+0)*260 + 2*h1]) = make_float2(rlo1.x+rhi1.x, rlo1.x-rhi1.x);
        *(float2*)(&xeo[(wl4+1)*260 + 2*h1]) = make_float2(rlo1.y+rhi1.y, rlo1.y-rhi1.y);
        *(float2*)(&xeo[(wl4+2)*260 + 2*h1]) = make_float2(rlo1.z+rhi1.z, rlo1.z-rhi1.z);
        *(float2*)(&xeo[(wl4+3)*260 + 2*h1]) = make_float2(rlo1.w+rhi1.w, rlo1.w-rhi1.w);
    };
    loadR(0);
    writeR();
    float4 acc[8];
    #pragma unroll
    for (int j = 0; j < 8; ++j) acc[j] = make_float4(0.f, 0.f, 0.f, 0.f);
    __syncthreads();  // xeo(0) ready
    for (int ph = 0; ph < 4; ++ph) {
        if (ph < 3) loadR(ph + 1);  // loads fly under compute
        #pragma unroll 4
        for (int wl = 0; wl < 16; ++wl) {
            int w = ph * 16 + wl;
            const float* xr = &xeo[wl * 260 + 4 * th];
            float4 d0  = *(const float4*)(xr);         // ve,vo for h=2th, 2th+1
            float4 d1  = *(const float4*)(xr + 128);   // ve,vo for h+64
            float4 tw0 = *(const float4*)(&Twid[w * 64 + q0]);
            float4 tw1 = *(const float4*)(&Twid[w * 64 + q0 + 4]);
            acc[0].x = fmaf(d0.x, tw0.x, acc[0].x); acc[0].y = fmaf(d0.x, tw0.y, acc[0].y);
            acc[0].z = fmaf(d0.y, tw0.z, acc[0].z); acc[0].w = fmaf(d0.y, tw0.w, acc[0].w);
            acc[1].x = fmaf(d0.x, tw1.x, acc[1].x); acc[1].y = fmaf(d0.x, tw1.y, acc[1].y);
            acc[1].z = fmaf(d0.y, tw1.z, acc[1].z); acc[1].w = fmaf(d0.y, tw1.w, acc[1].w);
            acc[2].x = fmaf(d0.z, tw0.x, acc[2].x); acc[2].y = fmaf(d0.z, tw0.y, acc[2].y);
            acc[2].z = fmaf(d0.w, tw0.z, acc[2].z); acc[2].w = fmaf(d0.w, tw0.w, acc[2].w);
            acc[3].x = fmaf(d0.z, tw1.x, acc[3].x); acc[3].y = fmaf(d0.z, tw1.y, acc[3].y);
            acc[3].z = fmaf(d0.w, tw1.z, acc[3].z); acc[3].w = fmaf(d0.w, tw1.w, acc[3].w);
            acc[4].x = fmaf(d1.x, tw0.x, acc[4].x); acc[4].y = fmaf(d1.x, tw0.y, acc[4].y);
            acc[4].z = fmaf(d1.y, tw0.z, acc[4].z); acc[4].w = fmaf(d1.y, tw0.w, acc[4].w);
            acc[5].x = fmaf(d1.x, tw1.x, acc[5].x); acc[5].y = fmaf(d1.x, tw1.y, acc[5].y);
            acc[5].z = fmaf(d1.y, tw1.z, acc[5].z); acc[5].w = fmaf(d1.y, tw1.w, acc[5].w);
            acc[6].x = fmaf(d1.z, tw0.x, acc[6].x); acc[6].y = fmaf(d1.z, tw0.y, acc[6].y);
            acc[6].z = fmaf(d1.w, tw0.z, acc[6].z); acc[6].w = fmaf(d1.w, tw0.w, acc[6].w);
            acc[7].x = fmaf(d1.z, tw1.x, acc[7].x); acc[7].y = fmaf(d1.z, tw1.y, acc[7].y);
            acc[7].z = fmaf(d1.w, tw1.z, acc[7].z); acc[7].w = fmaf(d1.w, tw1.w, acc[7].w);
        }
        __syncthreads();
        if (ph < 3) {
            writeR();
            __syncthreads();
        }
    }
    // In-register (h, h+64) fold -> Af planes, row stride 68.
    float* Af = smem;
    {
        int base = th * 68 + q0;
        *(float4*)(&Af[base])          = make_float4(acc[0].x+acc[4].x, acc[0].y+acc[4].y, acc[0].z+acc[4].z, acc[0].w+acc[4].w);
        *(float4*)(&Af[base + 4])      = make_float4(acc[1].x+acc[5].x, acc[1].y+acc[5].y, acc[1].z+acc[5].z, acc[1].w+acc[5].w);
        *(float4*)(&Af[2176 + base])   = make_float4(acc[0].x-acc[4].x, acc[0].y-acc[4].y, acc[0].z-acc[4].z, acc[0].w-acc[4].w);
        *(float4*)(&Af[2176 + base+4]) = make_float4(acc[1].x-acc[5].x, acc[1].y-acc[5].y, acc[1].z-acc[5].z, acc[1].w-acc[5].w);
        *(float4*)(&Af[4352 + base])   = make_float4(acc[2].x+acc[6].x, acc[2].y+acc[6].y, acc[2].z+acc[6].z, acc[2].w+acc[6].w);
        *(float4*)(&Af[4352 + base+4]) = make_float4(acc[3].x+acc[7].x, acc[3].y+acc[7].y, acc[3].z+acc[7].z, acc[3].w+acc[7].w);
        *(float4*)(&Af[6528 + base])   = make_float4(acc[2].x-acc[6].x, acc[2].y-acc[6].y, acc[2].z-acc[6].z, acc[2].w-acc[6].w);
        *(float4*)(&Af[6528 + base+4]) = make_float4(acc[3].x-acc[7].x, acc[3].y-acc[7].y, acc[3].z-acc[7].z, acc[3].w-acc[7].w);
    }
    __syncthreads();
    // ---- kB compute part (twiddles via rotation recurrence) ----
    {
        int k = t & 31, kxg = t >> 5;
        int kx0 = kxg * 4;
        int sig = k & 1;
        const float* pe = Af + sig * 2176;
        const float* po = Af + 4352 + sig * 2176;
        int a2 = (2 * k) & 127;
        float ca = tabs[a2], sa = tabs[129 + a2];
        float ce = 1.f, se = 0.f;
        float co_ = tabs[k], so_ = tabs[129 + k];
        float4 P1 = {0,0,0,0}, P2 = {0,0,0,0}, P3 = {0,0,0,0}, P4 = {0,0,0,0};
        for (int m = 0; m < 32; ++m) {
            float4 ae01 = *(const float4*)(pe + m * 68 + 2 * kx0);
            float4 ae23 = *(const float4*)(pe + m * 68 + 2 * kx0 + 4);
            float4 ao01 = *(const float4*)(po + m * 68 + 2 * kx0);
            float4 ao23 = *(const float4*)(po + m * 68 + 2 * kx0 + 4);
            P1.x = fmaf(ae01.x, ce, P1.x); P1.x = fmaf(ao01.x, co_, P1.x);
            P2.x = fmaf(ae01.y, se, P2.x); P2.x = fmaf(ao01.y, so_, P2.x);
            P3.x = fmaf(ae01.y, ce, P3.x); P3.x = fmaf(ao01.y, co_, P3.x);
            P4.x = fmaf(ae01.x, se, P4.x); P4.x = fmaf(ao01.x, so_, P4.x);
            P1.y = fmaf(ae01.z, ce, P1.y); P1.y = fmaf(ao01.z, co_, P1.y);
            P2.y = fmaf(ae01.w, se, P2.y); P2.y = fmaf(ao01.w, so_, P2.y);
            P3.y = fmaf(ae01.w, ce, P3.y); P3.y = fmaf(ao01.w, co_, P3.y);
            P4.y = fmaf(ae01.z, se, P4.y); P4.y = fmaf(ao01.z, so_, P4.y);
            P1.z = fmaf(ae23.x, ce, P1.z); P1.z = fmaf(ao23.x, co_, P1.z);
            P2.z = fmaf(ae23.y, se, P2.z); P2.z = fmaf(ao23.y, so_, P2.z);
            P3.z = fmaf(ae23.y, ce, P3.z); P3.z = fmaf(ao23.y, co_, P3.z);
            P4.z = fmaf(ae23.x, se, P4.z); P4.z = fmaf(ao23.x, so_, P4.z);
            P1.w = fmaf(ae23.z, ce, P1.w); P1.w = fmaf(ao23.z, co_, P1.w);
            P2.w = fmaf(ae23.w, se, P2.w); P2.w = fmaf(ao23.w, so_, P2.w);
            P3.w = fmaf(ae23.w, ce, P3.w); P3.w = fmaf(ao23.w, co_, P3.w);
            P4.w = fmaf(ae23.z, se, P4.w); P4.w = fmaf(ao23.z, so_, P4.w);
            float t1 = se * sa, t2 = ce * sa;
            float cen = fmaf(ce, ca, -t1);
            float sen = fmaf(se, ca, t2);
            ce = cen; se = sen;
            float t3 = so_ * sa, t4 = co_ * sa;
            float con = fmaf(co_, ca, -t3);
            float son = fmaf(so_, ca, t4);
            co_ = con; so_ = son;
        }
        float* xfb = XF + bc * 4096;
        *(float4*)(xfb + (k * 32 + kx0) * 2) =
            make_float4(P1.x + P2.x, P3.x - P4.x, P1.y + P2.y, P3.y - P4.y);
        *(float4*)(xfb + (k * 32 + kx0) * 2 + 4) =
            make_float4(P1.z + P2.z, P3.z - P4.z, P1.w + P2.w, P3.w - P4.w);
        if (k) {
            *(float4*)(xfb + ((64 - k) * 32 + kx0) * 2) =
                make_float4(P1.x - P2.x, P3.x + P4.x, P1.y - P2.y, P3.y + P4.y);
            *(float4*)(xfb + ((64 - k) * 32 + kx0) * 2 + 4) =
                make_float4(P1.z - P2.z, P3.z + P4.z, P1.w - P2.w, P3.w + P4.w);
        }
        if (t < 32) {
            int kx = t;
            float re = 0.f, im = 0.f;
            #pragma unroll 8
            for (int m = 0; m < 32; ++m) {
                float2 aep = *(const float2*)(&Af[       m * 68 + 2 * kx]);
                float2 aop = *(const float2*)(&Af[4352 + m * 68 + 2 * kx]);
                float sg = (m & 1) ? -1.f : 1.f;
                re = fmaf(sg, aep.x - aop.y, re);
                im = fmaf(sg, aep.y + aop.x, im);
            }
            xfb[(32 * 32 + kx) * 2]     = re;
            xfb[(32 * 32 + kx) * 2 + 1] = im;
        }
    }
}

// ---- kC v3: channel mix; thread=(co,mx); deep W-prefetch (3 chunks at entry)
__global__ __launch_bounds__(256, 4) void kC(const float* __restrict__ XF,
                                             const float* __restrict__ Wgt,
                                             float* __restrict__ YF0,
                                             float* __restrict__ YF1) {
    __shared__ float2 Xs[2048];  // [ci_l 8][b 16][mx 16], 16 KB
    int t = threadIdx.x;
    int bid = blockIdx.x;
    int cih = bid & 1;
    int mxh = (bid >> 1) & 1;
    int cot = (bid >> 2) & 3;
    int my  = (bid >> 4) & 31;
    int c   = bid >> 9;
    int co0 = cot * 16;
    int slotbase = (c * 32 + my) * 32 + mxh * 16;
    int mx = t & 15;
    int co_l = t >> 4;
    int co = co0 + co_l;
    int ci0 = cih * 32;
    float2 acc[16];
    #pragma unroll
    for (int i = 0; i < 16; ++i) acc[i] = make_float2(0.f, 0.f);
    const float* wp = Wgt + (size_t)c * 4194304 + (size_t)my * 32 + mxh * 16 + mx
                          + ((size_t)(ci0 * 64) + co) * 1024;
    float2 rw0[8], rw1[8], rw2[8], rw3[8], rx[8];
    auto loadW = [&](int cc, float2* rw) {
        #pragma unroll
        for (int j = 0; j < 8; ++j) {
            size_t off = (size_t)(cc * 8 + j) * 65536;
            rw[j].x = wp[off];
            rw[j].y = wp[off + 8388608];
        }
    };
    auto loadX = [&](int cc) {
        #pragma unroll
        for (int s = 0; s < 8; ++s) {
            int e = t + s * 256;
            int emx = e & 15, eb = (e >> 4) & 15, eci = e >> 8;
            int ci = ci0 + cc * 8 + eci;
            rx[s] = *(const float2*)(XF + ((size_t)(eb * 64 + ci) * 2048 + slotbase + emx) * 2);
        }
    };
    auto writeX = [&]() {
        #pragma unroll
        for (int s = 0; s < 8; ++s) Xs[t + s * 256] = rx[s];
    };
#define KC_COMPUTE(RW)                                                       \
    {                                                                        \
        _Pragma("unroll")                                                    \
        for (int j = 0; j < 8; ++j) {                                        \
            float2 w = RW[j];                                                \
            _Pragma("unroll")                                                \
            for (int b = 0; b < 16; ++b) {                                   \
                float2 xv = Xs[(j * 16 + b) * 16 + mx];                      \
                acc[b].x = fmaf(xv.x, w.x, acc[b].x);                        \
                acc[b].x = fmaf(-xv.y, w.y, acc[b].x);                       \
                acc[b].y = fmaf(xv.x, w.y, acc[b].y);                        \
                acc[b].y = fmaf(xv.y, w.x, acc[b].y);                        \
            }                                                                \
        }                                                                    \
    }
    loadX(0);
    loadW(0, rw0); loadW(1, rw1); loadW(2, rw2);  // deep prefetch
    writeX();
    __syncthreads();
    loadX(1);
    loadW(3, rw3);
    KC_COMPUTE(rw0);
    __syncthreads();
    writeX(); __syncthreads();
    loadX(2);
    KC_COMPUTE(rw1);
    __syncthreads();
    writeX(); __syncthreads();
    loadX(3);
    KC_COMPUTE(rw2);
    __syncthreads();
    writeX(); __syncthreads();
    KC_COMPUTE(rw3);
#undef KC_COMPUTE
    float* YF = cih ? YF1 : YF0;
    #pragma unroll
    for (int b = 0; b < 16; ++b) {
        *(float2*)(YF + ((size_t)(b * 64 + co) * 2048 + slotbase + mx) * 2) = acc[b];
    }
}

// ---- kDE: fused inverse H-DFT (folded) + inverse W-rDFT + bias ------------
// One block per bo = b*64+co (1024 blocks).
// Step 1: Q/R staging (as kD). Step 2: kD compute in regs.
// Step 3: write Z transposed into LDS Zt[q][h] (stride 132, overlays Q/R).
// Step 4: kE GEMM from LDS: Y[h][w] = sum_q Zt[q][h]*Ts[q][w] + bias.
__global__ __launch_bounds__(256) void kDE(const float* __restrict__ YF0,
                                           const float* __restrict__ YF1,
                                           const float* __restrict__ bias,
                                           float* __restrict__ out) {
    __shared__ float tabs[258];
    __shared__ __align__(16) float Ts[8192];  // [q 64][w 128], 32 KB
    __shared__ __align__(16) float U[8448];   // Q[0,2112)+R[2112,4224) -> Zt[64][132]
    build_tab(tabs);
    __syncthreads();
    int t = threadIdx.x;
    size_t bo = blockIdx.x;
    const float inv = 6.103515625e-05f;  // 1/16384
    #pragma unroll
    for (int i = 0; i < 32; ++i) {
        int e = t + i * 256;
        int q = e >> 7, w = e & 127;
        int k = q >> 1;
        int idx = (k * w) & 127;
        float val;
        if (q == 0)      val = inv;
        else if (q == 1) val = 0.f;
        else if (q & 1)  val = -2.f * inv * tabs[129 + idx];
        else             val =  2.f * inv * tabs[idx];
        Ts[e] = val;
    }
    float* Qs = U;
    float* Rs = U + 2112;
    const float* y0 = YF0 + bo * 4096;
    const float* y1 = YF1 + bo * 4096;
    for (int u = t; u < 528; u += 256) {
        int k = u >> 4, kxf = (u & 15) * 4;
        float4 a0 = *(const float4*)(y0 + k * 64 + kxf);
        float4 a1 = *(const float4*)(y1 + k * 64 + kxf);
        float4 a = make_float4(a0.x+a1.x, a0.y+a1.y, a0.z+a1.z, a0.w+a1.w);
        float4 Q, R;
        if (k == 0) { Q = a; R = make_float4(0.f, 0.f, 0.f, 0.f); }
        else if (k == 32) { Q = a; R = make_float4(-a.x, -a.y, -a.z, -a.w); }
        else {
            float4 b0 = *(const float4*)(y0 + (64 - k) * 64 + kxf);
            float4 b1 = *(const float4*)(y1 + (64 - k) * 64 + kxf);
            float4 bb = make_float4(b0.x+b1.x, b0.y+b1.y, b0.z+b1.z, b0.w+b1.w);
            Q = make_float4(a.x+bb.x, a.y+bb.y, a.z+bb.z, a.w+bb.w);
            R = make_float4(a.x-bb.x, a.y-bb.y, a.z-bb.z, a.w-bb.w);
        }
        *(float4*)(&Qs[k * 64 + kxf]) = Q;
        *(float4*)(&Rs[k * 64 + kxf]) = R;
    }
    __syncthreads();
    int hh = t >> 2;
    int kx0 = (t & 3) * 8;
    float4 Ee0 = {0,0,0,0}, Ee1 = {0,0,0,0}, Ee2 = {0,0,0,0}, Ee3 = {0,0,0,0};
    float4 Eo0 = {0,0,0,0}, Eo1 = {0,0,0,0}, Eo2 = {0,0,0,0}, Eo3 = {0,0,0,0};
    int idx = 0;
#define KD_BODY(E0, E1, E2, E3, kk)                                          \
    {                                                                        \
        float c = tabs[idx], s = tabs[129 + idx];                            \
        const float4* Qp = (const float4*)(&Qs[(kk) * 64 + kx0 * 2]);        \
        const float4* Rp = (const float4*)(&Rs[(kk) * 64 + kx0 * 2]);        \
        float4 Qv, Rv;                                                       \
        Qv = Qp[0]; Rv = Rp[0];                                              \
        E0.x = fmaf(c, Qv.x, E0.x); E0.x = fmaf(-s, Rv.y, E0.x);             \
        E0.y = fmaf(c, Qv.y, E0.y); E0.y = fmaf(s, Rv.x, E0.y);              \
        E0.z = fmaf(c, Qv.z, E0.z); E0.z = fmaf(-s, Rv.w, E0.z);             \
        E0.w = fmaf(c, Qv.w, E0.w); E0.w = fmaf(s, Rv.z, E0.w);              \
        Qv = Qp[1]; Rv = Rp[1];                                              \
        E1.x = fmaf(c, Qv.x, E1.x); E1.x = fmaf(-s, Rv.y, E1.x);             \
        E1.y = fmaf(c, Qv.y, E1.y); E1.y = fmaf(s, Rv.x, E1.y);              \
        E1.z = fmaf(c, Qv.z, E1.z); E1.z = fmaf(-s, Rv.w, E1.z);             \
        E1.w = fmaf(c, Qv.w, E1.w); E1.w = fmaf(s, Rv.z, E1.w);              \
        Qv = Qp[2]; Rv = Rp[2];                                              \
        E2.x = fmaf(c, Qv.x, E2.x); E2.x = fmaf(-s, Rv.y, E2.x);             \
        E2.y = fmaf(c, Qv.y, E2.y); E2.y = fmaf(s, Rv.x, E2.y);              \
        E2.z = fmaf(c, Qv.z, E2.z); E2.z = fmaf(-s, Rv.w, E2.z);             \
        E2.w = fmaf(c, Qv.w, E2.w); E2.w = fmaf(s, Rv.z, E2.w);              \
        Qv = Qp[3]; Rv = Rp[3];                                              \
        E3.x = fmaf(c, Qv.x, E3.x); E3.x = fmaf(-s, Rv.y, E3.x);             \
        E3.y = fmaf(c, Qv.y, E3.y); E3.y = fmaf(s, Rv.x, E3.y);              \
        E3.z = fmaf(c, Qv.z, E3.z); E3.z = fmaf(-s, Rv.w, E3.z);             \
        E3.w = fmaf(c, Qv.w, E3.w); E3.w = fmaf(s, Rv.z, E3.w);              \
        idx = (idx + hh) & 127;                                              \
    }
    for (int u = 0; u < 16; ++u) {
        KD_BODY(Ee0, Ee1, Ee2, Ee3, 2 * u);
        KD_BODY(Eo0, Eo1, Eo2, Eo3, 2 * u + 1);
    }
    KD_BODY(Ee0, Ee1, Ee2, Ee3, 32);
#undef KD_BODY
    __syncthreads();  // all Q/R reads done -> reuse U as Zt
    float* Zt = U;    // [q][h], stride 132
    {
        float* zr = &Zt[(2 * kx0) * 132 + hh];        // row hh
        float* zs = zr + 64;                          // row hh+64
        zr[0*132]  = Ee0.x + Eo0.x;  zs[0*132]  = Ee0.x - Eo0.x;
        zr[1*132]  = Ee0.y + Eo0.y;  zs[1*132]  = Ee0.y - Eo0.y;
        zr[2*132]  = Ee0.z + Eo0.z;  zs[2*132]  = Ee0.z - Eo0.z;
        zr[3*132]  = Ee0.w + Eo0.w;  zs[3*132]  = Ee0.w - Eo0.w;
        zr[4*132]  = Ee1.x + Eo1.x;  zs[4*132]  = Ee1.x - Eo1.x;
        zr[5*132]  = Ee1.y + Eo1.y;  zs[5*132]  = Ee1.y - Eo1.y;
        zr[6*132]  = Ee1.z + Eo1.z;  zs[6*132]  = Ee1.z - Eo1.z;
        zr[7*132]  = Ee1.w + Eo1.w;  zs[7*132]  = Ee1.w - Eo1.w;
        zr[8*132]  = Ee2.x + Eo2.x;  zs[8*132]  = Ee2.x - Eo2.x;
        zr[9*132]  = Ee2.y + Eo2.y;  zs[9*132]  = Ee2.y - Eo2.y;
        zr[10*132] = Ee2.z + Eo2.z;  zs[10*132] = Ee2.z - Eo2.z;
        zr[11*132] = Ee2.w + Eo2.w;  zs[11*132] = Ee2.w - Eo2.w;
        zr[12*132] = Ee3.x + Eo3.x;  zs[12*132] = Ee3.x - Eo3.x;
        zr[13*132] = Ee3.y + Eo3.y;  zs[13*132] = Ee3.y - Eo3.y;
        zr[14*132] = Ee3.z + Eo3.z;  zs[14*132] = Ee3.z - Eo3.z;
        zr[15*132] = Ee3.w + Eo3.w;  zs[15*132] = Ee3.w - Eo3.w;
    }
    __syncthreads();
    // kE GEMM: thread (w0 = (t&31)*4, h0 = (t>>5)*16): 16h x 4w outputs.
    int w0 = (t & 31) * 4;
    int h0 = (t >> 5) * 16;
    float4 a0 = {0,0,0,0}, a1 = {0,0,0,0}, a2 = {0,0,0,0}, a3 = {0,0,0,0};
    float4 a4 = {0,0,0,0}, a5 = {0,0,0,0}, a6 = {0,0,0,0}, a7 = {0,0,0,0};
    float4 a8 = {0,0,0,0}, a9 = {0,0,0,0}, a10 = {0,0,0,0}, a11 = {0,0,0,0};
    float4 a12 = {0,0,0,0}, a13 = {0,0,0,0}, a14 = {0,0,0,0}, a15 = {0,0,0,0};
#define KE_ROW(A, ZV) A.x = fmaf(ZV, tw.x, A.x); A.y = fmaf(ZV, tw.y, A.y); \
                      A.z = fmaf(ZV, tw.z, A.z); A.w = fmaf(ZV, tw.w, A.w);
    #pragma unroll 2
    for (int q = 0; q < 64; ++q) {
        const float4* zp = (const float4*)(&Zt[q * 132 + h0]);
        float4 za = zp[0], zb = zp[1], zc = zp[2], zd = zp[3];
        float4 tw = *(const float4*)(&Ts[q * 128 + w0]);
        KE_ROW(a0, za.x)  KE_ROW(a1, za.y)  KE_ROW(a2, za.z)  KE_ROW(a3, za.w)
        KE_ROW(a4, zb.x)  KE_ROW(a5, zb.y)  KE_ROW(a6, zb.z)  KE_ROW(a7, zb.w)
        KE_ROW(a8, zc.x)  KE_ROW(a9, zc.y)  KE_ROW(a10, zc.z) KE_ROW(a11, zc.w)
        KE_ROW(a12, zd.x) KE_ROW(a13, zd.y) KE_ROW(a14, zd.z) KE_ROW(a15, zd.w)
    }
#undef KE_ROW
    float bv = bias[(int)(bo & 63)];
    float* ob = out + ((size_t)(bo * 128 + h0)) * 128 + w0;
#define KE_ST(J, A) { float4 r = A; r.x += bv; r.y += bv; r.z += bv; r.w += bv; \
                      *(float4*)(ob + (size_t)(J) * 128) = r; }
    KE_ST(0, a0)   KE_ST(1, a1)   KE_ST(2, a2)   KE_ST(3, a3)
    KE_ST(4, a4)   KE_ST(5, a5)   KE_ST(6, a6)   KE_ST(7, a7)
    KE_ST(8, a8)   KE_ST(9, a9)   KE_ST(10, a10) KE_ST(11, a11)
    KE_ST(12, a12) KE_ST(13, a13) KE_ST(14, a14) KE_ST(15, a15)
#undef KE_ST
}

extern "C" void kernel_launch(void* const* d_in, const int* in_sizes, int n_in,
                              void* d_out, int out_size, void* d_ws, size_t ws_size,
                              hipStream_t stream) {
    (void)in_sizes; (void)n_in; (void)out_size; (void)ws_size;
    const float* x    = (const float*)d_in[0];
    const float* wgt  = (const float*)d_in[1];
    const float* bias = (const float*)d_in[2];
    float* outp   = (float*)d_out;
    char* ws = (char*)d_ws;
    float* bufXF  = (float*)(ws + (48u << 20));     // [48, 64 MiB)
    float* bufYF0 = (float*)(ws);                   // [0, 16 MiB)
    float* bufYF1 = (float*)(ws + (16u << 20));     // [16, 32 MiB)
    hipLaunchKernelGGL(kAB, dim3(1024), dim3(256), 0, stream, x, bufXF);
    hipLaunchKernelGGL(kC, dim3(1024), dim3(256), 0, stream, bufXF, wgt, bufYF0, bufYF1);
    hipLaunchKernelGGL(kDE, dim3(1024), dim3(256), 0, stream, bufYF0, bufYF1, bias, outp);
}

// Round 13
// 116.891 us; speedup vs baseline: 1.3469x; 1.0552x over previous
//
#include <hip/hip_runtime.h>

// FactorizedSpectralConv2d: B=16, CIN=COUT=64, H=W=128, MH=MW=32, super_res=1
// kAB (W-rDFT GEMM + folded H-DFT) -> kC (channel mix, deep W-prefetch)
// -> kDE (inv H-DFT folded + inv W-rDFT w-folded + bias, fused via LDS).
// ws layout (64 MiB): XF[48,64) ; YF0[0,16) ; YF1[16,32)

__device__ __forceinline__ void build_tab(float* tabs) {
    int t = threadIdx.x;
    if (t < 128) {
        float ang = (float)t * 0.049087385212340517f;  // 2*pi/128
        float s, c;
        sincosf(ang, &s, &c);
        tabs[t] = c;        // cos at [0..127]
        tabs[129 + t] = s;  // sin at [129..256]
    }
}

// ---- kAB: fused W-rDFT (per (b,ci) image) + folded H-DFT ------------------
__global__ __launch_bounds__(256) void kAB(const float* __restrict__ x,
                                           float* __restrict__ XF) {
    __shared__ float tabs[258];
    __shared__ __align__(16) float smem[8704];  // Twid[0,4096)|xeo[4096,8256); later Af[0,8704)
    build_tab(tabs);
    __syncthreads();
    int t = threadIdx.x;
    size_t bc = blockIdx.x;  // b*64+ci, 1024 blocks
    float* Twid = smem;
    float* xeo  = smem + 4096;
    #pragma unroll
    for (int i = 0; i < 16; ++i) {
        int e = t + i * 256;
        int w = e >> 6, q = e & 63, kx = q >> 1;
        int idx = (w * kx) & 127;
        Twid[e] = (q & 1) ? -tabs[129 + idx] : tabs[idx];
    }
    const float* xb = x + bc * 16384;
    int th = t & 31;   // h in {2th, 2th+1, 2th+64, 2th+65}
    int tq = t >> 5;   // q in [8tq, 8tq+8)
    int q0 = tq * 8;
    int wl4 = (t & 3) * 4;  // staging lanes
    int hb  = t >> 2;
    float4 rlo0, rhi0, rlo1, rhi1;
    auto loadR = [&](int ph) {
        rlo0 = *(const float4*)(xb + hb * 128 + ph * 16 + wl4);
        rhi0 = *(const float4*)(xb + hb * 128 + ph * 16 + wl4 + 64);
        rlo1 = *(const float4*)(xb + (64 + hb) * 128 + ph * 16 + wl4);
        rhi1 = *(const float4*)(xb + (64 + hb) * 128 + ph * 16 + wl4 + 64);
    };
    auto writeR = [&]() {
        int h0 = hb, h1 = 64 + hb;
        *(float2*)(&xeo[(wl4+0)*260 + 2*h0]) = make_float2(rlo0.x+rhi0.x, rlo0.x-rhi0.x);
        *(float2*)(&xeo[(wl4+1)*260 + 2*h0]) = make_float2(rlo0.y+rhi0.y, rlo0.y-rhi0.y);
        *(float2*)(&xeo[(wl4+2)*260 + 2*h0]) = make_float2(rlo0.z+rhi0.z, rlo0.z-rhi0.z);
        *(float2*)(&xeo[(wl4+3)*260 + 2*h0]) = make_float2(rlo0.w+rhi0.w, rlo0.w-rhi0.w);
        *(float2*)(&xeo[(wl4+0)*260 + 2*h1]) = make_float2(rlo1.x+rhi1.x, rlo1.x-rhi1.x);
        *(float2*)(&xeo[(wl4+1)*260 + 2*h1]) = make_float2(rlo1.y+rhi1.y, rlo1.y-rhi1.y);
        *(float2*)(&xeo[(wl4+2)*260 + 2*h1]) = make_float2(rlo1.z+rhi1.z, rlo1.z-rhi1.z);
        *(float2*)(&xeo[(wl4+3)*260 + 2*h1]) = make_float2(rlo1.w+rhi1.w, rlo1.w-rhi1.w);
    };
    loadR(0);
    writeR();
    float4 acc[8];
    #pragma unroll
    for (int j = 0; j < 8; ++j) acc[j] = make_float4(0.f, 0.f, 0.f, 0.f);
    __syncthreads();  // xeo(0) ready
    for (int ph = 0; ph < 4; ++ph) {
        if (ph < 3) loadR(ph + 1);  // loads fly under compute
        #pragma unroll 4
        for (int wl = 0; wl < 16; ++wl) {
            int w = ph * 16 + wl;
            const float* xr = &xeo[wl * 260 + 4 * th];
            float4 d0  = *(const float4*)(xr);         // ve,vo for h=2th, 2th+1
            float4 d1  = *(const float4*)(xr + 128);   // ve,vo for h+64
            float4 tw0 = *(const float4*)(&Twid[w * 64 + q0]);
            float4 tw1 = *(const float4*)(&Twid[w * 64 + q0 + 4]);
            acc[0].x = fmaf(d0.x, tw0.x, acc[0].x); acc[0].y = fmaf(d0.x, tw0.y, acc[0].y);
            acc[0].z = fmaf(d0.y, tw0.z, acc[0].z); acc[0].w = fmaf(d0.y, tw0.w, acc[0].w);
            acc[1].x = fmaf(d0.x, tw1.x, acc[1].x); acc[1].y = fmaf(d0.x, tw1.y, acc[1].y);
            acc[1].z = fmaf(d0.y, tw1.z, acc[1].z); acc[1].w = fmaf(d0.y, tw1.w, acc[1].w);
            acc[2].x = fmaf(d0.z, tw0.x, acc[2].x); acc[2].y = fmaf(d0.z, tw0.y, acc[2].y);
            acc[2].z = fmaf(d0.w, tw0.z, acc[2].z); acc[2].w = fmaf(d0.w, tw0.w, acc[2].w);
            acc[3].x = fmaf(d0.z, tw1.x, acc[3].x); acc[3].y = fmaf(d0.z, tw1.y, acc[3].y);
            acc[3].z = fmaf(d0.w, tw1.z, acc[3].z); acc[3].w = fmaf(d0.w, tw1.w, acc[3].w);
            acc[4].x = fmaf(d1.x, tw0.x, acc[4].x); acc[4].y = fmaf(d1.x, tw0.y, acc[4].y);
            acc[4].z = fmaf(d1.y, tw0.z, acc[4].z); acc[4].w = fmaf(d1.y, tw0.w, acc[4].w);
            acc[5].x = fmaf(d1.x, tw1.x, acc[5].x); acc[5].y = fmaf(d1.x, tw1.y, acc[5].y);
            acc[5].z = fmaf(d1.y, tw1.z, acc[5].z); acc[5].w = fmaf(d1.y, tw1.w, acc[5].w);
            acc[6].x = fmaf(d1.z, tw0.x, acc[6].x); acc[6].y = fmaf(d1.z, tw0.y, acc[6].y);
            acc[6].z = fmaf(d1.w, tw0.z, acc[6].z); acc[6].w = fmaf(d1.w, tw0.w, acc[6].w);
            acc[7].x = fmaf(d1.z, tw1.x, acc[7].x); acc[7].y = fmaf(d1.z, tw1.y, acc[7].y);
            acc[7].z = fmaf(d1.w, tw1.z, acc[7].z); acc[7].w = fmaf(d1.w, tw1.w, acc[7].w);
        }
        __syncthreads();
        if (ph < 3) {
            writeR();
            __syncthreads();
        }
    }
    // In-register (h, h+64) fold -> Af planes, row stride 68.
    float* Af = smem;
    {
        int base = th * 68 + q0;
        *(float4*)(&Af[base])          = make_float4(acc[0].x+acc[4].x, acc[0].y+acc[4].y, acc[0].z+acc[4].z, acc[0].w+acc[4].w);
        *(float4*)(&Af[base + 4])      = make_float4(acc[1].x+acc[5].x, acc[1].y+acc[5].y, acc[1].z+acc[5].z, acc[1].w+acc[5].w);
        *(float4*)(&Af[2176 + base])   = make_float4(acc[0].x-acc[4].x, acc[0].y-acc[4].y, acc[0].z-acc[4].z, acc[0].w-acc[4].w);
        *(float4*)(&Af[2176 + base+4]) = make_float4(acc[1].x-acc[5].x, acc[1].y-acc[5].y, acc[1].z-acc[5].z, acc[1].w-acc[5].w);
        *(float4*)(&Af[4352 + base])   = make_float4(acc[2].x+acc[6].x, acc[2].y+acc[6].y, acc[2].z+acc[6].z, acc[2].w+acc[6].w);
        *(float4*)(&Af[4352 + base+4]) = make_float4(acc[3].x+acc[7].x, acc[3].y+acc[7].y, acc[3].z+acc[7].z, acc[3].w+acc[7].w);
        *(float4*)(&Af[6528 + base])   = make_float4(acc[2].x-acc[6].x, acc[2].y-acc[6].y, acc[2].z-acc[6].z, acc[2].w-acc[6].w);
        *(float4*)(&Af[6528 + base+4]) = make_float4(acc[3].x-acc[7].x, acc[3].y-acc[7].y, acc[3].z-acc[7].z, acc[3].w-acc[7].w);
    }
    __syncthreads();
    // ---- kB compute part (twiddles via rotation recurrence) ----
    {
        int k = t & 31, kxg = t >> 5;
        int kx0 = kxg * 4;
        int sig = k & 1;
        const float* pe = Af + sig * 2176;
        const float* po = Af + 4352 + sig * 2176;
        int a2 = (2 * k) & 127;
        float ca = tabs[a2], sa = tabs[129 + a2];
        float ce = 1.f, se = 0.f;
        float co_ = tabs[k], so_ = tabs[129 + k];
        float4 P1 = {0,0,0,0}, P2 = {0,0,0,0}, P3 = {0,0,0,0}, P4 = {0,0,0,0};
        for (int m = 0; m < 32; ++m) {
            float4 ae01 = *(const float4*)(pe + m * 68 + 2 * kx0);
            float4 ae23 = *(const float4*)(pe + m * 68 + 2 * kx0 + 4);
            float4 ao01 = *(const float4*)(po + m * 68 + 2 * kx0);
            float4 ao23 = *(const float4*)(po + m * 68 + 2 * kx0 + 4);
            P1.x = fmaf(ae01.x, ce, P1.x); P1.x = fmaf(ao01.x, co_, P1.x);
            P2.x = fmaf(ae01.y, se, P2.x); P2.x = fmaf(ao01.y, so_, P2.x);
            P3.x = fmaf(ae01.y, ce, P3.x); P3.x = fmaf(ao01.y, co_, P3.x);
            P4.x = fmaf(ae01.x, se, P4.x); P4.x = fmaf(ao01.x, so_, P4.x);
            P1.y = fmaf(ae01.z, ce, P1.y); P1.y = fmaf(ao01.z, co_, P1.y);
            P2.y = fmaf(ae01.w, se, P2.y); P2.y = fmaf(ao01.w, so_, P2.y);
            P3.y = fmaf(ae01.w, ce, P3.y); P3.y = fmaf(ao01.w, co_, P3.y);
            P4.y = fmaf(ae01.z, se, P4.y); P4.y = fmaf(ao01.z, so_, P4.y);
            P1.z = fmaf(ae23.x, ce, P1.z); P1.z = fmaf(ao23.x, co_, P1.z);
            P2.z = fmaf(ae23.y, se, P2.z); P2.z = fmaf(ao23.y, so_, P2.z);
            P3.z = fmaf(ae23.y, ce, P3.z); P3.z = fmaf(ao23.y, co_, P3.z);
            P4.z = fmaf(ae23.x, se, P4.z); P4.z = fmaf(ao23.x, so_, P4.z);
            P1.w = fmaf(ae23.z, ce, P1.w); P1.w = fmaf(ao23.z, co_, P1.w);
            P2.w = fmaf(ae23.w, se, P2.w); P2.w = fmaf(ao23.w, so_, P2.w);
            P3.w = fmaf(ae23.w, ce, P3.w); P3.w = fmaf(ao23.w, co_, P3.w);
            P4.w = fmaf(ae23.z, se, P4.w); P4.w = fmaf(ao23.z, so_, P4.w);
            float t1 = se * sa, t2 = ce * sa;
            float cen = fmaf(ce, ca, -t1);
            float sen = fmaf(se, ca, t2);
            ce = cen; se = sen;
            float t3 = so_ * sa, t4 = co_ * sa;
            float con = fmaf(co_, ca, -t3);
            float son = fmaf(so_, ca, t4);
            co_ = con; so_ = son;
        }
        float* xfb = XF + bc * 4096;
        *(float4*)(xfb + (k * 32 + kx0) * 2) =
            make_float4(P1.x + P2.x, P3.x - P4.x, P1.y + P2.y, P3.y - P4.y);
        *(float4*)(xfb + (k * 32 + kx0) * 2 + 4) =
            make_float4(P1.z + P2.z, P3.z - P4.z, P1.w + P2.w, P3.w - P4.w);
        if (k) {
            *(float4*)(xfb + ((64 - k) * 32 + kx0) * 2) =
                make_float4(P1.x - P2.x, P3.x + P4.x, P1.y - P2.y, P3.y + P4.y);
            *(float4*)(xfb + ((64 - k) * 32 + kx0) * 2 + 4) =
                make_float4(P1.z - P2.z, P3.z + P4.z, P1.w - P2.w, P3.w + P4.w);
        }
        if (t < 32) {
            int kx = t;
            float re = 0.f, im = 0.f;
            #pragma unroll 8
            for (int m = 0; m < 32; ++m) {
                float2 aep = *(const float2*)(&Af[       m * 68 + 2 * kx]);
                float2 aop = *(const float2*)(&Af[4352 + m * 68 + 2 * kx]);
                float sg = (m & 1) ? -1.f : 1.f;
                re = fmaf(sg, aep.x - aop.y, re);
                im = fmaf(sg, aep.y + aop.x, im);
            }
            xfb[(32 * 32 + kx) * 2]     = re;
            xfb[(32 * 32 + kx) * 2 + 1] = im;
        }
    }
}

// ---- kC v3: channel mix; thread=(co,mx); deep W-prefetch (3 chunks at entry)
__global__ __launch_bounds__(256, 4) void kC(const float* __restrict__ XF,
                                             const float* __restrict__ Wgt,
                                             float* __restrict__ YF0,
                                             float* __restrict__ YF1) {
    __shared__ float2 Xs[2048];  // [ci_l 8][b 16][mx 16], 16 KB
    int t = threadIdx.x;
    int bid = blockIdx.x;
    int cih = bid & 1;
    int mxh = (bid >> 1) & 1;
    int cot = (bid >> 2) & 3;
    int my  = (bid >> 4) & 31;
    int c   = bid >> 9;
    int co0 = cot * 16;
    int slotbase = (c * 32 + my) * 32 + mxh * 16;
    int mx = t & 15;
    int co_l = t >> 4;
    int co = co0 + co_l;
    int ci0 = cih * 32;
    float2 acc[16];
    #pragma unroll
    for (int i = 0; i < 16; ++i) acc[i] = make_float2(0.f, 0.f);
    const float* wp = Wgt + (size_t)c * 4194304 + (size_t)my * 32 + mxh * 16 + mx
                          + ((size_t)(ci0 * 64) + co) * 1024;
    float2 rw0[8], rw1[8], rw2[8], rw3[8], rx[8];
    auto loadW = [&](int cc, float2* rw) {
        #pragma unroll
        for (int j = 0; j < 8; ++j) {
            size_t off = (size_t)(cc * 8 + j) * 65536;
            rw[j].x = wp[off];
            rw[j].y = wp[off + 8388608];
        }
    };
    auto loadX = [&](int cc) {
        #pragma unroll
        for (int s = 0; s < 8; ++s) {
            int e = t + s * 256;
            int emx = e & 15, eb = (e >> 4) & 15, eci = e >> 8;
            int ci = ci0 + cc * 8 + eci;
            rx[s] = *(const float2*)(XF + ((size_t)(eb * 64 + ci) * 2048 + slotbase + emx) * 2);
        }
    };
    auto writeX = [&]() {
        #pragma unroll
        for (int s = 0; s < 8; ++s) Xs[t + s * 256] = rx[s];
    };
#define KC_COMPUTE(RW)                                                       \
    {                                                                        \
        _Pragma("unroll")                                                    \
        for (int j = 0; j < 8; ++j) {                                        \
            float2 w = RW[j];                                                \
            _Pragma("unroll")                                                \
            for (int b = 0; b < 16; ++b) {                                   \
                float2 xv = Xs[(j * 16 + b) * 16 + mx];                      \
                acc[b].x = fmaf(xv.x, w.x, acc[b].x);                        \
                acc[b].x = fmaf(-xv.y, w.y, acc[b].x);                       \
                acc[b].y = fmaf(xv.x, w.y, acc[b].y);                        \
                acc[b].y = fmaf(xv.y, w.x, acc[b].y);                        \
            }                                                                \
        }                                                                    \
    }
    loadX(0);
    loadW(0, rw0); loadW(1, rw1); loadW(2, rw2);  // deep prefetch
    writeX();
    __syncthreads();
    loadX(1);
    loadW(3, rw3);
    KC_COMPUTE(rw0);
    __syncthreads();
    writeX(); __syncthreads();
    loadX(2);
    KC_COMPUTE(rw1);
    __syncthreads();
    writeX(); __syncthreads();
    loadX(3);
    KC_COMPUTE(rw2);
    __syncthreads();
    writeX(); __syncthreads();
    KC_COMPUTE(rw3);
#undef KC_COMPUTE
    float* YF = cih ? YF1 : YF0;
    #pragma unroll
    for (int b = 0; b < 16; ++b) {
        *(float2*)(YF + ((size_t)(b * 64 + co) * 2048 + slotbase + mx) * 2) = acc[b];
    }
}

// ---- kDE: fused inv H-DFT (folded) + inv W-rDFT (w-folded) + bias ---------
// One block per bo = b*64+co (1024 blocks).
// Step 1: Q/R staging. Step 2: kD compute in regs. Step 3: Zt[q][h] in LDS
// (stride 132, overlays Q/R). Step 4: kE GEMM with w-fold:
//   Ts[q][w+64] = (-1)^(q>>1) Ts[q][w]  ->  Ee/Eo by k-parity,
//   Y[w] = Ee+Eo, Y[w+64] = Ee-Eo. Ts only [64][64] (16 KB).
__global__ __launch_bounds__(256) void kDE(const float* __restrict__ YF0,
                                           const float* __restrict__ YF1,
                                           const float* __restrict__ bias,
                                           float* __restrict__ out) {
    __shared__ float tabs[258];
    __shared__ __align__(16) float Ts[4096];  // [q 64][w 64], 16 KB
    __shared__ __align__(16) float U[8448];   // Q[0,2112)+R[2112,4224) -> Zt[64][132]
    build_tab(tabs);
    __syncthreads();
    int t = threadIdx.x;
    size_t bo = blockIdx.x;
    const float inv = 6.103515625e-05f;  // 1/16384
    #pragma unroll
    for (int i = 0; i < 16; ++i) {
        int e = t + i * 256;
        int q = e >> 6, w = e & 63;
        int k = q >> 1;
        int idx = (k * w) & 127;
        float val;
        if (q == 0)      val = inv;
        else if (q == 1) val = 0.f;
        else if (q & 1)  val = -2.f * inv * tabs[129 + idx];
        else             val =  2.f * inv * tabs[idx];
        Ts[e] = val;
    }
    float* Qs = U;
    float* Rs = U + 2112;
    const float* y0 = YF0 + bo * 4096;
    const float* y1 = YF1 + bo * 4096;
    for (int u = t; u < 528; u += 256) {
        int k = u >> 4, kxf = (u & 15) * 4;
        float4 a0 = *(const float4*)(y0 + k * 64 + kxf);
        float4 a1 = *(const float4*)(y1 + k * 64 + kxf);
        float4 a = make_float4(a0.x+a1.x, a0.y+a1.y, a0.z+a1.z, a0.w+a1.w);
        float4 Q, R;
        if (k == 0) { Q = a; R = make_float4(0.f, 0.f, 0.f, 0.f); }
        else if (k == 32) { Q = a; R = make_float4(-a.x, -a.y, -a.z, -a.w); }
        else {
            float4 b0 = *(const float4*)(y0 + (64 - k) * 64 + kxf);
            float4 b1 = *(const float4*)(y1 + (64 - k) * 64 + kxf);
            float4 bb = make_float4(b0.x+b1.x, b0.y+b1.y, b0.z+b1.z, b0.w+b1.w);
            Q = make_float4(a.x+bb.x, a.y+bb.y, a.z+bb.z, a.w+bb.w);
            R = make_float4(a.x-bb.x, a.y-bb.y, a.z-bb.z, a.w-bb.w);
        }
        *(float4*)(&Qs[k * 64 + kxf]) = Q;
        *(float4*)(&Rs[k * 64 + kxf]) = R;
    }
    __syncthreads();
    int hh = t >> 2;
    int kx0 = (t & 3) * 8;
    float4 Ee0 = {0,0,0,0}, Ee1 = {0,0,0,0}, Ee2 = {0,0,0,0}, Ee3 = {0,0,0,0};
    float4 Eo0 = {0,0,0,0}, Eo1 = {0,0,0,0}, Eo2 = {0,0,0,0}, Eo3 = {0,0,0,0};
    int idx = 0;
#define KD_BODY(E0, E1, E2, E3, kk)                                          \
    {                                                                        \
        float c = tabs[idx], s = tabs[129 + idx];                            \
        const float4* Qp = (const float4*)(&Qs[(kk) * 64 + kx0 * 2]);        \
        const float4* Rp = (const float4*)(&Rs[(kk) * 64 + kx0 * 2]);        \
        float4 Qv, Rv;                                                       \
        Qv = Qp[0]; Rv = Rp[0];                                              \
        E0.x = fmaf(c, Qv.x, E0.x); E0.x = fmaf(-s, Rv.y, E0.x);             \
        E0.y = fmaf(c, Qv.y, E0.y); E0.y = fmaf(s, Rv.x, E0.y);              \
        E0.z = fmaf(c, Qv.z, E0.z); E0.z = fmaf(-s, Rv.w, E0.z);             \
        E0.w = fmaf(c, Qv.w, E0.w); E0.w = fmaf(s, Rv.z, E0.w);              \
        Qv = Qp[1]; Rv = Rp[1];                                              \
        E1.x = fmaf(c, Qv.x, E1.x); E1.x = fmaf(-s, Rv.y, E1.x);             \
        E1.y = fmaf(c, Qv.y, E1.y); E1.y = fmaf(s, Rv.x, E1.y);              \
        E1.z = fmaf(c, Qv.z, E1.z); E1.z = fmaf(-s, Rv.w, E1.z);             \
        E1.w = fmaf(c, Qv.w, E1.w); E1.w = fmaf(s, Rv.z, E1.w);              \
        Qv = Qp[2]; Rv = Rp[2];                                              \
        E2.x = fmaf(c, Qv.x, E2.x); E2.x = fmaf(-s, Rv.y, E2.x);             \
        E2.y = fmaf(c, Qv.y, E2.y); E2.y = fmaf(s, Rv.x, E2.y);              \
        E2.z = fmaf(c, Qv.z, E2.z); E2.z = fmaf(-s, Rv.w, E2.z);             \
        E2.w = fmaf(c, Qv.w, E2.w); E2.w = fmaf(s, Rv.z, E2.w);              \
        Qv = Qp[3]; Rv = Rp[3];                                              \
        E3.x = fmaf(c, Qv.x, E3.x); E3.x = fmaf(-s, Rv.y, E3.x);             \
        E3.y = fmaf(c, Qv.y, E3.y); E3.y = fmaf(s, Rv.x, E3.y);              \
        E3.z = fmaf(c, Qv.z, E3.z); E3.z = fmaf(-s, Rv.w, E3.z);             \
        E3.w = fmaf(c, Qv.w, E3.w); E3.w = fmaf(s, Rv.z, E3.w);              \
        idx = (idx + hh) & 127;                                              \
    }
    for (int u = 0; u < 16; ++u) {
        KD_BODY(Ee0, Ee1, Ee2, Ee3, 2 * u);
        KD_BODY(Eo0, Eo1, Eo2, Eo3, 2 * u + 1);
    }
    KD_BODY(Ee0, Ee1, Ee2, Ee3, 32);
#undef KD_BODY
    __syncthreads();  // all Q/R reads done -> reuse U as Zt
    float* Zt = U;    // [q][h], stride 132
    {
        float* zr = &Zt[(2 * kx0) * 132 + hh];        // row hh
        float* zs = zr + 64;                          // row hh+64
        zr[0*132]  = Ee0.x + Eo0.x;  zs[0*132]  = Ee0.x - Eo0.x;
        zr[1*132]  = Ee0.y + Eo0.y;  zs[1*132]  = Ee0.y - Eo0.y;
        zr[2*132]  = Ee0.z + Eo0.z;  zs[2*132]  = Ee0.z - Eo0.z;
        zr[3*132]  = Ee0.w + Eo0.w;  zs[3*132]  = Ee0.w - Eo0.w;
        zr[4*132]  = Ee1.x + Eo1.x;  zs[4*132]  = Ee1.x - Eo1.x;
        zr[5*132]  = Ee1.y + Eo1.y;  zs[5*132]  = Ee1.y - Eo1.y;
        zr[6*132]  = Ee1.z + Eo1.z;  zs[6*132]  = Ee1.z - Eo1.z;
        zr[7*132]  = Ee1.w + Eo1.w;  zs[7*132]  = Ee1.w - Eo1.w;
        zr[8*132]  = Ee2.x + Eo2.x;  zs[8*132]  = Ee2.x - Eo2.x;
        zr[9*132]  = Ee2.y + Eo2.y;  zs[9*132]  = Ee2.y - Eo2.y;
        zr[10*132] = Ee2.z + Eo2.z;  zs[10*132] = Ee2.z - Eo2.z;
        zr[11*132] = Ee2.w + Eo2.w;  zs[11*132] = Ee2.w - Eo2.w;
        zr[12*132] = Ee3.x + Eo3.x;  zs[12*132] = Ee3.x - Eo3.x;
        zr[13*132] = Ee3.y + Eo3.y;  zs[13*132] = Ee3.y - Eo3.y;
        zr[14*132] = Ee3.z + Eo3.z;  zs[14*132] = Ee3.z - Eo3.z;
        zr[15*132] = Ee3.w + Eo3.w;  zs[15*132] = Ee3.w - Eo3.w;
    }
    __syncthreads();
    // kE GEMM with w-fold: thread (w0 = (t&31)*2, h0 = (t>>5)*16).
    // We[j] accumulates even-k, Wo[j] odd-k; Y[w]=We+Wo, Y[w+64]=We-Wo.
    int w0 = (t & 31) * 2;
    int h0 = (t >> 5) * 16;
    float2 We[16], Wo[16];
    #pragma unroll
    for (int j = 0; j < 16; ++j) { We[j] = make_float2(0.f, 0.f); Wo[j] = make_float2(0.f, 0.f); }
#define KE_K(E, K)                                                            \
    {                                                                         \
        const float4* zpe = (const float4*)(&Zt[(2*(K)) * 132 + h0]);         \
        const float4* zpo = (const float4*)(&Zt[(2*(K)+1) * 132 + h0]);       \
        float2 twe = *(const float2*)(&Ts[(2*(K)) * 64 + w0]);                \
        float2 two = *(const float2*)(&Ts[(2*(K)+1) * 64 + w0]);              \
        float4 e0 = zpe[0], e1 = zpe[1], e2 = zpe[2], e3 = zpe[3];            \
        float4 o0 = zpo[0], o1 = zpo[1], o2 = zpo[2], o3 = zpo[3];            \
        E[0].x  = fmaf(e0.x, twe.x, E[0].x);  E[0].x  = fmaf(o0.x, two.x, E[0].x);   \
        E[0].y  = fmaf(e0.x, twe.y, E[0].y);  E[0].y  = fmaf(o0.x, two.y, E[0].y);   \
        E[1].x  = fmaf(e0.y, twe.x, E[1].x);  E[1].x  = fmaf(o0.y, two.x, E[1].x);   \
        E[1].y  = fmaf(e0.y, twe.y, E[1].y);  E[1].y  = fmaf(o0.y, two.y, E[1].y);   \
        E[2].x  = fmaf(e0.z, twe.x, E[2].x);  E[2].x  = fmaf(o0.z, two.x, E[2].x);   \
        E[2].y  = fmaf(e0.z, twe.y, E[2].y);  E[2].y  = fmaf(o0.z, two.y, E[2].y);   \
        E[3].x  = fmaf(e0.w, twe.x, E[3].x);  E[3].x  = fmaf(o0.w, two.x, E[3].x);   \
        E[3].y  = fmaf(e0.w, twe.y, E[3].y);  E[3].y  = fmaf(o0.w, two.y, E[3].y);   \
        E[4].x  = fmaf(e1.x, twe.x, E[4].x);  E[4].x  = fmaf(o1.x, two.x, E[4].x);   \
        E[4].y  = fmaf(e1.x, twe.y, E[4].y);  E[4].y  = fmaf(o1.x, two.y, E[4].y);   \
        E[5].x  = fmaf(e1.y, twe.x, E[5].x);  E[5].x  = fmaf(o1.y, two.x, E[5].x);   \
        E[5].y  = fmaf(e1.y, twe.y, E[5].y);  E[5].y  = fmaf(o1.y, two.y, E[5].y);   \
        E[6].x  = fmaf(e1.z, twe.x, E[6].x);  E[6].x  = fmaf(o1.z, two.x, E[6].x);   \
        E[6].y  = fmaf(e1.z, twe.y, E[6].y);  E[6].y  = fmaf(o1.z, two.y, E[6].y);   \
        E[7].x  = fmaf(e1.w, twe.x, E[7].x);  E[7].x  = fmaf(o1.w, two.x, E[7].x);   \
        E[7].y  = fmaf(e1.w, twe.y, E[7].y);  E[7].y  = fmaf(o1.w, two.y, E[7].y);   \
        E[8].x  = fmaf(e2.x, twe.x, E[8].x);  E[8].x  = fmaf(o2.x, two.x, E[8].x);   \
        E[8].y  = fmaf(e2.x, twe.y, E[8].y);  E[8].y  = fmaf(o2.x, two.y, E[8].y);   \
        E[9].x  = fmaf(e2.y, twe.x, E[9].x);  E[9].x  = fmaf(o2.y, two.x, E[9].x);   \
        E[9].y  = fmaf(e2.y, twe.y, E[9].y);  E[9].y  = fmaf(o2.y, two.y, E[9].y);   \
        E[10].x = fmaf(e2.z, twe.x, E[10].x); E[10].x = fmaf(o2.z, two.x, E[10].x);  \
        E[10].y = fmaf(e2.z, twe.y, E[10].y); E[10].y = fmaf(o2.z, two.y, E[10].y);  \
        E[11].x = fmaf(e2.w, twe.x, E[11].x); E[11].x = fmaf(o2.w, two.x, E[11].x);  \
        E[11].y = fmaf(e2.w, twe.y, E[11].y); E[11].y = fmaf(o2.w, two.y, E[11].y);  \
        E[12].x = fmaf(e3.x, twe.x, E[12].x); E[12].x = fmaf(o3.x, two.x, E[12].x);  \
        E[12].y = fmaf(e3.x, twe.y, E[12].y); E[12].y = fmaf(o3.x, two.y, E[12].y);  \
        E[13].x = fmaf(e3.y, twe.x, E[13].x); E[13].x = fmaf(o3.y, two.x, E[13].x);  \
        E[13].y = fmaf(e3.y, twe.y, E[13].y); E[13].y = fmaf(o3.y, two.y, E[13].y);  \
        E[14].x = fmaf(e3.z, twe.x, E[14].x); E[14].x = fmaf(o3.z, two.x, E[14].x);  \
        E[14].y = fmaf(e3.z, twe.y, E[14].y); E[14].y = fmaf(o3.z, two.y, E[14].y);  \
        E[15].x = fmaf(e3.w, twe.x, E[15].x); E[15].x = fmaf(o3.w, two.x, E[15].x);  \
        E[15].y = fmaf(e3.w, twe.y, E[15].y); E[15].y = fmaf(o3.w, two.y, E[15].y);  \
    }
    #pragma unroll 2
    for (int u = 0; u < 16; ++u) {
        KE_K(We, 2 * u);       // k even
        KE_K(Wo, 2 * u + 1);   // k odd
    }
#undef KE_K
    float bv = bias[(int)(bo & 63)];
    float* ob = out + ((size_t)(bo * 128 + h0)) * 128;
    #pragma unroll
    for (int j = 0; j < 16; ++j) {
        float2 lo = make_float2(We[j].x + Wo[j].x + bv, We[j].y + Wo[j].y + bv);
        float2 hi = make_float2(We[j].x - Wo[j].x + bv, We[j].y - Wo[j].y + bv);
        *(float2*)(ob + (size_t)j * 128 + w0)      = lo;
        *(float2*)(ob + (size_t)j * 128 + w0 + 64) = hi;
    }
}

extern "C" void kernel_launch(void* const* d_in, const int* in_sizes, int n_in,
                              void* d_out, int out_size, void* d_ws, size_t ws_size,
                              hipStream_t stream) {
    (void)in_sizes; (void)n_in; (void)out_size; (void)ws_size;
    const float* x    = (const float*)d_in[0];
    const float* wgt  = (const float*)d_in[1];
    const float* bias = (const float*)d_in[2];
    float* outp   = (float*)d_out;
    char* ws = (char*)d_ws;
    float* bufXF  = (float*)(ws + (48u << 20));     // [48, 64 MiB)
    float* bufYF0 = (float*)(ws);                   // [0, 16 MiB)
    float* bufYF1 = (float*)(ws + (16u << 20));     // [16, 32 MiB)
    hipLaunchKernelGGL(kAB, dim3(1024), dim3(256), 0, stream, x, bufXF);
    hipLaunchKernelGGL(kC, dim3(1024), dim3(256), 0, stream, bufXF, wgt, bufYF0, bufYF1);
    hipLaunchKernelGGL(kDE, dim3(1024), dim3(256), 0, stream, bufYF0, bufYF1, bias, outp);
}